// Round 1
// baseline (868.123 us; speedup 1.0000x reference)
//
#include <hip/hip_runtime.h>
#include <stdint.h>

typedef unsigned short u16;
typedef __attribute__((ext_vector_type(8))) short s16x8;
typedef __attribute__((ext_vector_type(8))) unsigned short u16x8;
typedef __attribute__((ext_vector_type(4))) unsigned short u16x4;
typedef __attribute__((ext_vector_type(4))) float fx4;
typedef __bf16 bf16x8 __attribute__((ext_vector_type(8)));

#define SEQ 2048
#define HID 4096
#define NHEAD 32
#define HDIM 128
// proj row length = 3*HID
#define P3H 12288

__device__ __forceinline__ u16 f2bf(float f) {
  unsigned u = __builtin_bit_cast(unsigned, f);
  u += 0x7fffu + ((u >> 16) & 1u);          // RNE
  return (u16)(u >> 16);
}
__device__ __forceinline__ float bf2f(u16 h) {
  unsigned u = ((unsigned)h) << 16;
  return __builtin_bit_cast(float, u);
}
__device__ __forceinline__ void gload_lds16(const void* g, void* l) {
  __builtin_amdgcn_global_load_lds((const __attribute__((address_space(1))) void*)g,
                                   (__attribute__((address_space(3))) void*)l, 16, 0, 0);
}
__device__ __forceinline__ fx4 mfma16(s16x8 a, s16x8 b, fx4 c) {
  return __builtin_amdgcn_mfma_f32_16x16x32_bf16(
      __builtin_bit_cast(bf16x8, a), __builtin_bit_cast(bf16x8, b), c, 0, 0, 0);
}

// ---------------- f32 -> bf16 convert ----------------
__global__ void k_cvt(const float* __restrict__ src, u16* __restrict__ dst, int n4) {
  int i = blockIdx.x * blockDim.x + threadIdx.x;
  if (i >= n4) return;
  float4 v = reinterpret_cast<const float4*>(src)[i];
  u16x4 o;
  o[0] = f2bf(v.x); o[1] = f2bf(v.y); o[2] = f2bf(v.z); o[3] = f2bf(v.w);
  reinterpret_cast<u16x4*>(dst)[i] = o;
}

// ---------------- QKV GEMM: C[m][n] = sum_k A[m][k] * W[n][k] ----------------
// A [4096][4096] bf16, W [12288][4096] bf16, C [4096][12288] bf16.
// m97 structure: 128x128 tile, BK=32, 4 waves (2x2), 16x16x32 MFMA, 4x4 frags/wave.
__global__ void __launch_bounds__(256) k_gemm_qkv(const u16* __restrict__ A,
                                                  const u16* __restrict__ W,
                                                  u16* __restrict__ C) {
  __shared__ u16 As[128 * 32];
  __shared__ u16 Bs[128 * 32];
  const int t = threadIdx.x;
  const int m0 = blockIdx.y * 128;
  const int n0 = blockIdx.x * 128;
  const int w = t >> 6, lane = t & 63;
  const int li = lane & 15, lg = lane >> 4;
  const int wr = (w >> 1) * 64, wc = (w & 1) * 64;

  fx4 acc[4][4];
#pragma unroll
  for (int a = 0; a < 4; a++)
#pragma unroll
    for (int b = 0; b < 4; b++) acc[a][b] = fx4{0.f, 0.f, 0.f, 0.f};

  const int srow = t >> 2;           // staging row (0..63), +64 on 2nd call
  const int scol = (t & 3) * 8;      // staging col (8 bf16 = 16B)

  for (int k0 = 0; k0 < HID; k0 += 32) {
    gload_lds16(A + (size_t)(m0 + srow) * HID + k0 + scol,        &As[(size_t)t * 8]);
    gload_lds16(A + (size_t)(m0 + 64 + srow) * HID + k0 + scol,   &As[(size_t)(256 + t) * 8]);
    gload_lds16(W + (size_t)(n0 + srow) * HID + k0 + scol,        &Bs[(size_t)t * 8]);
    gload_lds16(W + (size_t)(n0 + 64 + srow) * HID + k0 + scol,   &Bs[(size_t)(256 + t) * 8]);
    asm volatile("s_waitcnt vmcnt(0)" ::: "memory");
    __syncthreads();

    s16x8 af[4], bfr[4];
#pragma unroll
    for (int mi = 0; mi < 4; mi++)
      af[mi] = *reinterpret_cast<const s16x8*>(&As[(wr + mi * 16 + li) * 32 + lg * 8]);
#pragma unroll
    for (int ni = 0; ni < 4; ni++)
      bfr[ni] = *reinterpret_cast<const s16x8*>(&Bs[(wc + ni * 16 + li) * 32 + lg * 8]);
#pragma unroll
    for (int mi = 0; mi < 4; mi++)
#pragma unroll
      for (int ni = 0; ni < 4; ni++)
        acc[mi][ni] = mfma16(af[mi], bfr[ni], acc[mi][ni]);
    __syncthreads();
  }

  // C/D layout: col = lane&15, row = (lane>>4)*4 + j  (m89-verified)
#pragma unroll
  for (int mi = 0; mi < 4; mi++)
#pragma unroll
    for (int ni = 0; ni < 4; ni++)
#pragma unroll
      for (int j = 0; j < 4; j++) {
        int r = m0 + wr + mi * 16 + lg * 4 + j;
        int cc = n0 + wc + ni * 16 + li;
        C[(size_t)r * P3H + cc] = f2bf(acc[mi][ni][j]);
      }
}

// ---------------- RoPE: proj -> q,k in [B,NH,S,HD] (bf16) ----------------
// one wave handles one (b,s,h); lane = rotation pair index d (0..63)
__global__ void k_rope(const u16* __restrict__ proj, u16* __restrict__ q,
                       u16* __restrict__ k, const int* __restrict__ pos_ids) {
  int t = blockIdx.x * 256 + threadIdx.x;
  int d = t & 63;
  int h = (t >> 6) & 31;
  int s = (t >> 11) & 2047;
  int b = t >> 22;
  int prow = b * SEQ + s;
  const u16* pr = proj + (size_t)prow * P3H;
  float q1 = bf2f(pr[h * HDIM + d]);
  float q2 = bf2f(pr[h * HDIM + d + 64]);
  float k1 = bf2f(pr[HID + h * HDIM + d]);
  float k2 = bf2f(pr[HID + h * HDIM + d + 64]);
  float p = (float)pos_ids[prow];
  // inv_freq = 10000^(-d/64) = 2^(-d * log2(1e4)/64)
  float invf = exp2f(-(float)d * 0.2076205059304601f);
  float ang = p * invf;
  float sn, cs;
  sincosf(ang, &sn, &cs);
  size_t base = ((size_t)(b * NHEAD + h) * SEQ + s) * HDIM + d;
  q[base]      = f2bf(q1 * cs - q2 * sn);
  q[base + 64] = f2bf(q2 * cs + q1 * sn);
  k[base]      = f2bf(k1 * cs - k2 * sn);
  k[base + 64] = f2bf(k2 * cs + k1 * sn);
}

// ---------------- V transpose: proj v-part -> vt [B,NH,HD,S] (bf16) ----------------
// lane owns one d; copies 8 consecutive s -> one 16B store per lane
__global__ void k_vtrans(const u16* __restrict__ proj, u16* __restrict__ vt) {
  int wid = (blockIdx.x * 256 + threadIdx.x) >> 6;
  int lane = threadIdx.x & 63;
  int half = wid & 1;
  int s8 = (wid >> 1) & 255;
  int h = (wid >> 9) & 31;
  int b = wid >> 14;
  int d = half * 64 + lane;
  int s0 = s8 * 8;
  u16x8 v;
#pragma unroll
  for (int r = 0; r < 8; r++)
    v[r] = proj[(size_t)(b * SEQ + s0 + r) * P3H + 2 * HID + h * HDIM + d];
  *reinterpret_cast<u16x8*>(&vt[((size_t)(b * NHEAD + h) * HDIM + d) * SEQ + s0]) = v;
}

// ---------------- Flash attention (causal) ----------------
// block = (b, h, 64 q-rows); 4 waves x 16 rows. KV tiles of 64.
// K_lds [64][128] and Vt_lds [128][64] with 16B-block XOR swizzle (both-sides: pre-
// swizzled global source + linear gload_lds dest + swizzled ds_read). P via per-wave
// swizzled LDS. Online softmax in exp2 domain.
__global__ void __launch_bounds__(256) k_attn(const u16* __restrict__ q,
                                              const u16* __restrict__ k,
                                              const u16* __restrict__ vt,
                                              float* __restrict__ out) {
  __shared__ u16 Ks[64 * 128];
  __shared__ u16 Vs[128 * 64];
  __shared__ u16 Ps[4][16 * 64];
  const int t = threadIdx.x;
  const int w = t >> 6, lane = t & 63;
  const int li = lane & 15, lg = lane >> 4;
  const int qb = blockIdx.x;
  const int h = blockIdx.y, b = blockIdx.z;
  const int q0 = qb * 64;
  const int qw = q0 + w * 16;
  const size_t bh = (size_t)(b * NHEAD + h);
  const u16* qp = q + bh * SEQ * HDIM;
  const u16* kp = k + bh * SEQ * HDIM;
  const u16* vp = vt + bh * HDIM * SEQ;

  // Q fragments (A-operand): lane li = q-row, 8 contiguous k at lg*8
  s16x8 aq[4];
#pragma unroll
  for (int kk = 0; kk < 4; kk++)
    aq[kk] = *reinterpret_cast<const s16x8*>(&qp[(size_t)(qw + li) * HDIM + kk * 32 + lg * 8]);

  fx4 Oacc[8];
#pragma unroll
  for (int nd = 0; nd < 8; nd++) Oacc[nd] = fx4{0.f, 0.f, 0.f, 0.f};
  float mrun[4], lrun[4];
#pragma unroll
  for (int j = 0; j < 4; j++) { mrun[j] = -1e30f; lrun[j] = 0.f; }

  const int krow_t = t >> 4, kblk_t = t & 15;   // K stage: 16 blocks/row
  const int vrow_t = t >> 3, vblk_t = t & 7;    // V stage: 8 blocks/row
  const float SC2 = 0.12752551286084110f;       // (1/sqrt(128)) * log2(e)

  const int nt = qb + 1;
  for (int tk = 0; tk < nt; tk++) {
    const int kv0 = tk * 64;
#pragma unroll
    for (int c = 0; c < 4; c++) {   // K tile: 64x128
      int row = c * 16 + krow_t;
      int cb = kblk_t ^ (row & 7);  // inverse-swizzled global source
      gload_lds16(kp + (size_t)(kv0 + row) * HDIM + cb * 8, &Ks[(size_t)(c * 256 + t) * 8]);
    }
#pragma unroll
    for (int c = 0; c < 4; c++) {   // Vt tile: 128x64
      int row = c * 32 + vrow_t;    // d
      int cb = vblk_t ^ (row & 7);
      gload_lds16(vp + (size_t)row * SEQ + kv0 + cb * 8, &Vs[(size_t)(c * 256 + t) * 8]);
    }
    asm volatile("s_waitcnt vmcnt(0)" ::: "memory");
    __syncthreads();

    // S = Q K^T  (16 q-rows x 64 kv)
    fx4 sc[4];
#pragma unroll
    for (int n = 0; n < 4; n++) {
      fx4 z = fx4{0.f, 0.f, 0.f, 0.f};
      int r = n * 16 + li;
#pragma unroll
      for (int kk = 0; kk < 4; kk++) {
        s16x8 bk = *reinterpret_cast<const s16x8*>(&Ks[r * 128 + (((kk * 4 + lg) ^ (r & 7)) << 3)]);
        z = mfma16(aq[kk], bk, z);
      }
      sc[n] = z;
    }
    // scale (exp2 domain) + causal mask on diagonal tile
    const bool diag = (tk == qb);
#pragma unroll
    for (int n = 0; n < 4; n++)
#pragma unroll
      for (int j = 0; j < 4; j++) {
        float sv = sc[n][j] * SC2;
        if (diag) {
          int kvg = kv0 + n * 16 + li;
          int qg = qw + lg * 4 + j;
          if (kvg > qg) sv = -1e30f;
        }
        sc[n][j] = sv;
      }
    // row max across 4 n-tiles then across the 16-lane col group
    float alpha[4], rsum[4];
#pragma unroll
    for (int j = 0; j < 4; j++) {
      float mv = fmaxf(fmaxf(sc[0][j], sc[1][j]), fmaxf(sc[2][j], sc[3][j]));
      mv = fmaxf(mv, __shfl_xor(mv, 1));
      mv = fmaxf(mv, __shfl_xor(mv, 2));
      mv = fmaxf(mv, __shfl_xor(mv, 4));
      mv = fmaxf(mv, __shfl_xor(mv, 8));
      float mnew = fmaxf(mrun[j], mv);
      alpha[j] = exp2f(mrun[j] - mnew);
      mrun[j] = mnew;
      rsum[j] = 0.f;
    }
    // P = exp2(s - m): write to per-wave swizzled LDS, accumulate row sums
#pragma unroll
    for (int n = 0; n < 4; n++)
#pragma unroll
      for (int j = 0; j < 4; j++) {
        float pv = exp2f(sc[n][j] - mrun[j]);
        rsum[j] += pv;
        int row = lg * 4 + j;
        int blk = (n * 2 + (li >> 3)) ^ (row & 7);
        Ps[w][row * 64 + (blk << 3) + (li & 7)] = f2bf(pv);
      }
#pragma unroll
    for (int j = 0; j < 4; j++) {
      float rv = rsum[j];
      rv += __shfl_xor(rv, 1);
      rv += __shfl_xor(rv, 2);
      rv += __shfl_xor(rv, 4);
      rv += __shfl_xor(rv, 8);
      lrun[j] = lrun[j] * alpha[j] + rv;
    }
    // rescale O
#pragma unroll
    for (int nd = 0; nd < 8; nd++)
#pragma unroll
      for (int j = 0; j < 4; j++) Oacc[nd][j] *= alpha[j];
    // O += P V : A = P rows (from Ps), B = V (from swizzled Vt_lds)
    s16x8 ap[2];
#pragma unroll
    for (int kvc = 0; kvc < 2; kvc++)
      ap[kvc] = *reinterpret_cast<const s16x8*>(&Ps[w][li * 64 + (((kvc * 4 + lg) ^ (li & 7)) << 3)]);
#pragma unroll
    for (int nd = 0; nd < 8; nd++) {
      int dr = nd * 16 + li;
#pragma unroll
      for (int kvc = 0; kvc < 2; kvc++) {
        s16x8 bv = *reinterpret_cast<const s16x8*>(&Vs[dr * 64 + (((kvc * 4 + lg) ^ (dr & 7)) << 3)]);
        Oacc[nd] = mfma16(ap[kvc], bv, Oacc[nd]);
      }
    }
    __syncthreads();
  }

  // epilogue: normalize and store f32 [B,S,H]
#pragma unroll
  for (int j = 0; j < 4; j++) {
    float rl = 1.0f / lrun[j];
    int s = qw + lg * 4 + j;
    float* op = out + ((size_t)(b * SEQ) + s) * HID + h * HDIM;
#pragma unroll
    for (int nd = 0; nd < 8; nd++) op[nd * 16 + li] = Oacc[nd][j] * rl;
  }
}

extern "C" void kernel_launch(void* const* d_in, const int* in_sizes, int n_in,
                              void* d_out, int out_size, void* d_ws, size_t ws_size,
                              hipStream_t stream) {
  const float* hidden = (const float*)d_in[0];
  const float* wpack = (const float*)d_in[1];
  // d_in[2] = attention_mask (pure causal -1e9 upper triangle) — reproduced analytically
  const int* pos = (const int*)d_in[3];
  float* out = (float*)d_out;

  char* ws = (char*)d_ws;
  // region A [0, 128 MiB): hidden_bf(32) + wpack_bf(96) during GEMM;
  //                        reused as q(32) + k(32) + vt(32) afterwards.
  // region B [128, 224 MiB): proj (96 MiB)
  u16* hid_bf = (u16*)ws;
  u16* wp_bf = (u16*)(ws + ((size_t)32 << 20));
  u16* qb = (u16*)ws;
  u16* kb = (u16*)(ws + ((size_t)32 << 20));
  u16* vtb = (u16*)(ws + ((size_t)64 << 20));
  u16* proj = (u16*)(ws + ((size_t)128 << 20));

  k_cvt<<<(HID * HID / 4 + 255) / 256, 256, 0, stream>>>(hidden, hid_bf, HID * HID / 4);
  k_cvt<<<(P3H * HID / 4 + 255) / 256, 256, 0, stream>>>(wpack, wp_bf, P3H * HID / 4);

  dim3 gg(P3H / 128, (2 * SEQ) / 128);
  k_gemm_qkv<<<gg, 256, 0, stream>>>(hid_bf, wp_bf, proj);

  k_rope<<<(2 * SEQ * NHEAD * 64) / 256, 256, 0, stream>>>(proj, qb, kb, pos);
  k_vtrans<<<(2 * NHEAD * (SEQ / 8) * 2) / 4, 256, 0, stream>>>(proj, vtb);

  dim3 ga(SEQ / 64, NHEAD, 2);
  k_attn<<<ga, 256, 0, stream>>>(qb, kb, vtb, out);
}

// Round 2
// 765.974 us; speedup vs baseline: 1.1334x; 1.1334x over previous
//
#include <hip/hip_runtime.h>
#include <stdint.h>

typedef unsigned short u16;
typedef __attribute__((ext_vector_type(8))) short s16x8;
typedef __attribute__((ext_vector_type(8))) unsigned short u16x8;
typedef __attribute__((ext_vector_type(4))) unsigned short u16x4;
typedef __attribute__((ext_vector_type(4))) float fx4;
typedef __bf16 bf16x8 __attribute__((ext_vector_type(8)));

#define SEQ 2048
#define HID 4096
#define NHEAD 32
#define HDIM 128
#define P3H 12288
#define NKT 64  // K-tiles of 64 in the GEMM (4096/64)

__device__ __forceinline__ u16 f2bf(float f) {
  unsigned u = __builtin_bit_cast(unsigned, f);
  u += 0x7fffu + ((u >> 16) & 1u);          // RNE
  return (u16)(u >> 16);
}
__device__ __forceinline__ float bf2f(u16 h) {
  unsigned u = ((unsigned)h) << 16;
  return __builtin_bit_cast(float, u);
}
__device__ __forceinline__ void gload_lds16(const void* g, void* l) {
  __builtin_amdgcn_global_load_lds((const __attribute__((address_space(1))) void*)g,
                                   (__attribute__((address_space(3))) void*)l, 16, 0, 0);
}
__device__ __forceinline__ fx4 mfma16(s16x8 a, s16x8 b, fx4 c) {
  return __builtin_amdgcn_mfma_f32_16x16x32_bf16(
      __builtin_bit_cast(bf16x8, a), __builtin_bit_cast(bf16x8, b), c, 0, 0, 0);
}

// ---------------- f32 -> bf16 convert ----------------
__global__ void k_cvt(const float* __restrict__ src, u16* __restrict__ dst, int n4) {
  int i = blockIdx.x * blockDim.x + threadIdx.x;
  if (i >= n4) return;
  float4 v = reinterpret_cast<const float4*>(src)[i];
  u16x4 o;
  o[0] = f2bf(v.x); o[1] = f2bf(v.y); o[2] = f2bf(v.z); o[3] = f2bf(v.w);
  reinterpret_cast<u16x4*>(dst)[i] = o;
}

// ---------------- QKV GEMM: 256x256 8-phase template ----------------
// C[m][n] = sum_k A[m][k] * W[n][k]; A [4096][4096], W [12288][4096], C bf16 [4096][12288]
// 8 waves (2M x 4N), per-wave 128x64 out, BK=64, double-buffered LDS w/ XOR swizzle,
// counted vmcnt (T1+T2+T3+T4+T5 per guide §5/§5.5).

// stage 128 rows (one half-tile, 2 x global_load_lds per thread) of a 256x64 LDS tile.
// g must be pre-offset to (tile_row0 * HID + k0). Swizzle: LDS[row][blk] holds
// global blk ^ (row&7); dest stays linear (rule #21).
__device__ __forceinline__ void stage_half(const u16* __restrict__ g, u16* l, int r0, int t) {
#pragma unroll
  for (int c = 0; c < 2; c++) {
    int row = r0 + c * 64 + (t >> 3);
    int blk = (t & 7) ^ ((t >> 3) & 7);
    gload_lds16(g + (size_t)row * HID + blk * 8, l + row * 64 + (t & 7) * 8);
  }
}

#define SBAR do { __builtin_amdgcn_sched_barrier(0); __builtin_amdgcn_s_barrier(); \
                  __builtin_amdgcn_sched_barrier(0); } while (0)
#define LGKM0 do { asm volatile("s_waitcnt lgkmcnt(0)" ::: "memory"); \
                   __builtin_amdgcn_sched_barrier(0); } while (0)

#define LDA_QUAD(qm) do { \
  _Pragma("unroll") for (int mi = 0; mi < 4; mi++) \
  _Pragma("unroll") for (int ks = 0; ks < 2; ks++) { \
    int row = wrr + (qm) * 64 + mi * 16 + li; \
    aA[mi][ks] = *(const s16x8*)&Al[row * 64 + (((ks * 4 + lg) ^ (row & 7)) << 3)]; \
  } } while (0)

#define LDB_QUAD(qn) do { \
  _Pragma("unroll") for (int ni = 0; ni < 2; ni++) \
  _Pragma("unroll") for (int ks = 0; ks < 2; ks++) { \
    int row = wcc + (qn) * 32 + ni * 16 + li; \
    aB[qn][ni][ks] = *(const s16x8*)&Bl[row * 64 + (((ks * 4 + lg) ^ (row & 7)) << 3)]; \
  } } while (0)

#define MMA_QUAD(qm, qn) do { \
  _Pragma("unroll") for (int ks = 0; ks < 2; ks++) \
  _Pragma("unroll") for (int mi = 0; mi < 4; mi++) \
  _Pragma("unroll") for (int ni = 0; ni < 2; ni++) \
    acc[(qm) * 4 + mi][(qn) * 2 + ni] = \
        mfma16(aA[mi][ks], aB[qn][ni][ks], acc[(qm) * 4 + mi][(qn) * 2 + ni]); \
  } while (0)

__global__ void __launch_bounds__(512, 2) k_gemm_qkv(const u16* __restrict__ A,
                                                     const u16* __restrict__ W,
                                                     u16* __restrict__ C) {
  __shared__ u16 SM[2][2][256 * 64];   // [buf][A|B][256 rows x 64 k] = 128 KiB
  const int t = threadIdx.x;
  const int lane = t & 63;
  const int w = t >> 6;
  const int li = lane & 15, lg = lane >> 4;
  const int wr = w >> 2, wc = w & 3;
  const int wrr = wr * 128, wcc = wc * 64;

  // XCD-chunked swizzle (768 wgs, 768%8==0 -> bijective)
  const int cpx = gridDim.x >> 3;
  const int swz = (blockIdx.x & 7) * cpx + (blockIdx.x >> 3);
  const int bm = swz / 48, bn = swz - bm * 48;
  const int m0 = bm * 256, n0 = bn * 256;

  const u16* Ag = A + (size_t)m0 * HID;
  const u16* Wg = W + (size_t)n0 * HID;

  fx4 acc[8][4];
#pragma unroll
  for (int i = 0; i < 8; i++)
#pragma unroll
    for (int j = 0; j < 4; j++) acc[i][j] = fx4{0.f, 0.f, 0.f, 0.f};
  s16x8 aA[4][2], aB[2][2][2];

  // ---- prologue: B(0), A(0), B(1) staged; wait for kt=0 resident (4 loads may fly)
  stage_half(Wg, &SM[0][1][0], 0, t);
  stage_half(Wg, &SM[0][1][0], 128, t);
  stage_half(Ag, &SM[0][0][0], 0, t);
  stage_half(Ag, &SM[0][0][0], 128, t);
  stage_half(Wg + 64, &SM[1][1][0], 0, t);
  stage_half(Wg + 64, &SM[1][1][0], 128, t);
  asm volatile("s_waitcnt vmcnt(4)" ::: "memory");
  SBAR;

  for (int kt = 0; kt < NKT; kt++) {
    const int cur = kt & 1;
    u16* Al = &SM[cur][0][0];
    u16* Bl = &SM[cur][1][0];
    u16* Anxt = &SM[cur ^ 1][0][0];
    const u16* Agn = Ag + (size_t)(kt + 1) * 64;   // next A K-chunk
    const u16* Wgn = Wg + (size_t)(kt + 2) * 64;   // next-next B K-chunk

    // ---- phase 0: A-quad0 + B-quad0 reads; stage A(kt+1) half0
    LDA_QUAD(0);
    LDB_QUAD(0);
    if (kt + 1 < NKT) stage_half(Agn, Anxt, 0, t);
    asm volatile("s_waitcnt lgkmcnt(8)" ::: "memory");
    SBAR;
    LGKM0;
    __builtin_amdgcn_s_setprio(1);
    MMA_QUAD(0, 0);
    __builtin_amdgcn_s_setprio(0);
    SBAR;

    // ---- phase 1: B-quad1 reads; stage A(kt+1) half1
    LDB_QUAD(1);
    if (kt + 1 < NKT) stage_half(Agn, Anxt, 128, t);
    SBAR;
    LGKM0;
    __builtin_amdgcn_s_setprio(1);
    MMA_QUAD(0, 1);
    __builtin_amdgcn_s_setprio(0);
    SBAR;

    // ---- phase 2: A-quad1 reads; stage B(kt+2) half0 (B of cur buf is dead)
    LDA_QUAD(1);
    if (kt + 2 < NKT) stage_half(Wgn, Bl, 0, t);
    SBAR;
    LGKM0;
    __builtin_amdgcn_s_setprio(1);
    MMA_QUAD(1, 1);
    __builtin_amdgcn_s_setprio(0);
    SBAR;

    // ---- phase 3: no reads; stage B(kt+2) half1; counted vmcnt
    if (kt + 2 < NKT) stage_half(Wgn, Bl, 128, t);
    SBAR;
    LGKM0;
    __builtin_amdgcn_s_setprio(1);
    MMA_QUAD(1, 0);
    __builtin_amdgcn_s_setprio(0);
    if (kt + 2 < NKT) {
      asm volatile("s_waitcnt vmcnt(4)" ::: "memory");   // leave B(kt+2) in flight
    } else {
      asm volatile("s_waitcnt vmcnt(0)" ::: "memory");   // tail: drain
    }
    SBAR;
  }

  // ---- epilogue: C write (bf16)
#pragma unroll
  for (int mi = 0; mi < 8; mi++)
#pragma unroll
    for (int ni = 0; ni < 4; ni++)
#pragma unroll
      for (int j = 0; j < 4; j++) {
        int r = m0 + wrr + mi * 16 + lg * 4 + j;
        int c = n0 + wcc + ni * 16 + li;
        C[(size_t)r * P3H + c] = f2bf(acc[mi][ni][j]);
      }
}

// ---------------- RoPE: proj -> q,k in [B,NH,S,HD] (bf16) ----------------
__global__ void k_rope(const u16* __restrict__ proj, u16* __restrict__ q,
                       u16* __restrict__ k, const int* __restrict__ pos_ids) {
  int t = blockIdx.x * 256 + threadIdx.x;
  int d = t & 63;
  int h = (t >> 6) & 31;
  int s = (t >> 11) & 2047;
  int b = t >> 22;
  int prow = b * SEQ + s;
  const u16* pr = proj + (size_t)prow * P3H;
  float q1 = bf2f(pr[h * HDIM + d]);
  float q2 = bf2f(pr[h * HDIM + d + 64]);
  float k1 = bf2f(pr[HID + h * HDIM + d]);
  float k2 = bf2f(pr[HID + h * HDIM + d + 64]);
  float p = (float)pos_ids[prow];
  float invf = exp2f(-(float)d * 0.2076205059304601f);
  float ang = p * invf;
  float sn, cs;
  sincosf(ang, &sn, &cs);
  size_t base = ((size_t)(b * NHEAD + h) * SEQ + s) * HDIM + d;
  q[base]      = f2bf(q1 * cs - q2 * sn);
  q[base + 64] = f2bf(q2 * cs + q1 * sn);
  k[base]      = f2bf(k1 * cs - k2 * sn);
  k[base + 64] = f2bf(k2 * cs + k1 * sn);
}

// ---------------- V transpose: proj v-part -> vt [B,NH,HD,S] (bf16) ----------------
__global__ void k_vtrans(const u16* __restrict__ proj, u16* __restrict__ vt) {
  int wid = (blockIdx.x * 256 + threadIdx.x) >> 6;
  int lane = threadIdx.x & 63;
  int half = wid & 1;
  int s8 = (wid >> 1) & 255;
  int h = (wid >> 9) & 31;
  int b = wid >> 14;
  int d = half * 64 + lane;
  int s0 = s8 * 8;
  u16x8 v;
#pragma unroll
  for (int r = 0; r < 8; r++)
    v[r] = proj[(size_t)(b * SEQ + s0 + r) * P3H + 2 * HID + h * HDIM + d];
  *reinterpret_cast<u16x8*>(&vt[((size_t)(b * NHEAD + h) * HDIM + d) * SEQ + s0]) = v;
}

// ---------------- Flash attention (causal) ----------------
__global__ void __launch_bounds__(256) k_attn(const u16* __restrict__ q,
                                              const u16* __restrict__ k,
                                              const u16* __restrict__ vt,
                                              float* __restrict__ out) {
  __shared__ u16 Ks[64 * 128];
  __shared__ u16 Vs[128 * 64];
  __shared__ u16 Ps[4][16 * 64];
  const int t = threadIdx.x;
  const int w = t >> 6, lane = t & 63;
  const int li = lane & 15, lg = lane >> 4;
  const int qb = blockIdx.x;
  const int h = blockIdx.y, b = blockIdx.z;
  const int q0 = qb * 64;
  const int qw = q0 + w * 16;
  const size_t bh = (size_t)(b * NHEAD + h);
  const u16* qp = q + bh * SEQ * HDIM;
  const u16* kp = k + bh * SEQ * HDIM;
  const u16* vp = vt + bh * HDIM * SEQ;

  s16x8 aq[4];
#pragma unroll
  for (int kk = 0; kk < 4; kk++)
    aq[kk] = *reinterpret_cast<const s16x8*>(&qp[(size_t)(qw + li) * HDIM + kk * 32 + lg * 8]);

  fx4 Oacc[8];
#pragma unroll
  for (int nd = 0; nd < 8; nd++) Oacc[nd] = fx4{0.f, 0.f, 0.f, 0.f};
  float mrun[4], lrun[4];
#pragma unroll
  for (int j = 0; j < 4; j++) { mrun[j] = -1e30f; lrun[j] = 0.f; }

  const int krow_t = t >> 4, kblk_t = t & 15;
  const int vrow_t = t >> 3, vblk_t = t & 7;
  const float SC2 = 0.12752551286084110f;       // (1/sqrt(128)) * log2(e)

  const int nt = qb + 1;
  for (int tk = 0; tk < nt; tk++) {
    const int kv0 = tk * 64;
#pragma unroll
    for (int c = 0; c < 4; c++) {
      int row = c * 16 + krow_t;
      int cb = kblk_t ^ (row & 7);
      gload_lds16(kp + (size_t)(kv0 + row) * HDIM + cb * 8, &Ks[(size_t)(c * 256 + t) * 8]);
    }
#pragma unroll
    for (int c = 0; c < 4; c++) {
      int row = c * 32 + vrow_t;
      int cb = vblk_t ^ (row & 7);
      gload_lds16(vp + (size_t)row * SEQ + kv0 + cb * 8, &Vs[(size_t)(c * 256 + t) * 8]);
    }
    asm volatile("s_waitcnt vmcnt(0)" ::: "memory");
    __syncthreads();

    fx4 sc[4];
#pragma unroll
    for (int n = 0; n < 4; n++) {
      fx4 z = fx4{0.f, 0.f, 0.f, 0.f};
      int r = n * 16 + li;
#pragma unroll
      for (int kk = 0; kk < 4; kk++) {
        s16x8 bk = *reinterpret_cast<const s16x8*>(&Ks[r * 128 + (((kk * 4 + lg) ^ (r & 7)) << 3)]);
        z = mfma16(aq[kk], bk, z);
      }
      sc[n] = z;
    }
    const bool diag = (tk == qb);
#pragma unroll
    for (int n = 0; n < 4; n++)
#pragma unroll
      for (int j = 0; j < 4; j++) {
        float sv = sc[n][j] * SC2;
        if (diag) {
          int kvg = kv0 + n * 16 + li;
          int qg = qw + lg * 4 + j;
          if (kvg > qg) sv = -1e30f;
        }
        sc[n][j] = sv;
      }
    float alpha[4], rsum[4];
#pragma unroll
    for (int j = 0; j < 4; j++) {
      float mv = fmaxf(fmaxf(sc[0][j], sc[1][j]), fmaxf(sc[2][j], sc[3][j]));
      mv = fmaxf(mv, __shfl_xor(mv, 1));
      mv = fmaxf(mv, __shfl_xor(mv, 2));
      mv = fmaxf(mv, __shfl_xor(mv, 4));
      mv = fmaxf(mv, __shfl_xor(mv, 8));
      float mnew = fmaxf(mrun[j], mv);
      alpha[j] = exp2f(mrun[j] - mnew);
      mrun[j] = mnew;
      rsum[j] = 0.f;
    }
#pragma unroll
    for (int n = 0; n < 4; n++)
#pragma unroll
      for (int j = 0; j < 4; j++) {
        float pv = exp2f(sc[n][j] - mrun[j]);
        rsum[j] += pv;
        int row = lg * 4 + j;
        int blk = (n * 2 + (li >> 3)) ^ (row & 7);
        Ps[w][row * 64 + (blk << 3) + (li & 7)] = f2bf(pv);
      }
#pragma unroll
    for (int j = 0; j < 4; j++) {
      float rv = rsum[j];
      rv += __shfl_xor(rv, 1);
      rv += __shfl_xor(rv, 2);
      rv += __shfl_xor(rv, 4);
      rv += __shfl_xor(rv, 8);
      lrun[j] = lrun[j] * alpha[j] + rv;
    }
#pragma unroll
    for (int nd = 0; nd < 8; nd++)
#pragma unroll
      for (int j = 0; j < 4; j++) Oacc[nd][j] *= alpha[j];
    s16x8 ap[2];
#pragma unroll
    for (int kvc = 0; kvc < 2; kvc++)
      ap[kvc] = *reinterpret_cast<const s16x8*>(&Ps[w][li * 64 + (((kvc * 4 + lg) ^ (li & 7)) << 3)]);
#pragma unroll
    for (int nd = 0; nd < 8; nd++) {
      int dr = nd * 16 + li;
#pragma unroll
      for (int kvc = 0; kvc < 2; kvc++) {
        s16x8 bv = *reinterpret_cast<const s16x8*>(&Vs[dr * 64 + (((kvc * 4 + lg) ^ (dr & 7)) << 3)]);
        Oacc[nd] = mfma16(ap[kvc], bv, Oacc[nd]);
      }
    }
    __syncthreads();
  }

#pragma unroll
  for (int j = 0; j < 4; j++) {
    float rl = 1.0f / lrun[j];
    int s = qw + lg * 4 + j;
    float* op = out + ((size_t)(b * SEQ) + s) * HID + h * HDIM;
#pragma unroll
    for (int nd = 0; nd < 8; nd++) op[nd * 16 + li] = Oacc[nd][j] * rl;
  }
}

extern "C" void kernel_launch(void* const* d_in, const int* in_sizes, int n_in,
                              void* d_out, int out_size, void* d_ws, size_t ws_size,
                              hipStream_t stream) {
  const float* hidden = (const float*)d_in[0];
  const float* wpack = (const float*)d_in[1];
  const int* pos = (const int*)d_in[3];
  float* out = (float*)d_out;

  char* ws = (char*)d_ws;
  u16* hid_bf = (u16*)ws;
  u16* wp_bf = (u16*)(ws + ((size_t)32 << 20));
  u16* qb = (u16*)ws;
  u16* kb = (u16*)(ws + ((size_t)32 << 20));
  u16* vtb = (u16*)(ws + ((size_t)64 << 20));
  u16* proj = (u16*)(ws + ((size_t)128 << 20));

  k_cvt<<<(HID * HID / 4 + 255) / 256, 256, 0, stream>>>(hidden, hid_bf, HID * HID / 4);
  k_cvt<<<(P3H * HID / 4 + 255) / 256, 256, 0, stream>>>(wpack, wp_bf, P3H * HID / 4);

  // 256x256 tiles: (4096/256) x (12288/256) = 16 x 48 = 768 wgs
  k_gemm_qkv<<<768, 512, 0, stream>>>(hid_bf, wp_bf, proj);

  k_rope<<<(2 * SEQ * NHEAD * 64) / 256, 256, 0, stream>>>(proj, qb, kb, pos);
  k_vtrans<<<(2 * NHEAD * (SEQ / 8) * 2) / 4, 256, 0, stream>>>(proj, vtb);

  dim3 ga(SEQ / 64, NHEAD, 2);
  k_attn<<<ga, 256, 0, stream>>>(qb, kb, vtb, out);
}

// Round 3
// 751.115 us; speedup vs baseline: 1.1558x; 1.0198x over previous
//
#include <hip/hip_runtime.h>
#include <stdint.h>

typedef unsigned short u16;
typedef __attribute__((ext_vector_type(8))) short s16x8;
typedef __attribute__((ext_vector_type(8))) unsigned short u16x8;
typedef __attribute__((ext_vector_type(4))) unsigned short u16x4;
typedef __attribute__((ext_vector_type(4))) float fx4;
typedef __bf16 bf16x8 __attribute__((ext_vector_type(8)));

#define SEQ 2048
#define HID 4096
#define NHEAD 32
#define HDIM 128
#define P3H 12288
#define NKT 64  // K-tiles of 64 in the GEMM (4096/64)

__device__ __forceinline__ u16 f2bf(float f) {
  unsigned u = __builtin_bit_cast(unsigned, f);
  u += 0x7fffu + ((u >> 16) & 1u);          // RNE
  return (u16)(u >> 16);
}
__device__ __forceinline__ float bf2f(u16 h) {
  unsigned u = ((unsigned)h) << 16;
  return __builtin_bit_cast(float, u);
}
__device__ __forceinline__ void gload_lds16(const void* g, void* l) {
  __builtin_amdgcn_global_load_lds((const __attribute__((address_space(1))) void*)g,
                                   (__attribute__((address_space(3))) void*)l, 16, 0, 0);
}
__device__ __forceinline__ fx4 mfma16(s16x8 a, s16x8 b, fx4 c) {
  return __builtin_amdgcn_mfma_f32_16x16x32_bf16(
      __builtin_bit_cast(bf16x8, a), __builtin_bit_cast(bf16x8, b), c, 0, 0, 0);
}

// ---------------- f32 -> bf16 convert ----------------
__global__ void k_cvt(const float* __restrict__ src, u16* __restrict__ dst, int n4) {
  int i = blockIdx.x * blockDim.x + threadIdx.x;
  if (i >= n4) return;
  float4 v = reinterpret_cast<const float4*>(src)[i];
  u16x4 o;
  o[0] = f2bf(v.x); o[1] = f2bf(v.y); o[2] = f2bf(v.z); o[3] = f2bf(v.w);
  reinterpret_cast<u16x4*>(dst)[i] = o;
}

// ---------------- QKV GEMM: 256x256 8-phase template ----------------
__device__ __forceinline__ void stage_half(const u16* __restrict__ g, u16* l, int r0, int t) {
#pragma unroll
  for (int c = 0; c < 2; c++) {
    int row = r0 + c * 64 + (t >> 3);
    int blk = (t & 7) ^ ((t >> 3) & 7);
    gload_lds16(g + (size_t)row * HID + blk * 8, l + row * 64 + (t & 7) * 8);
  }
}

// opening barrier: plain (let the scheduler move things in)
#define BAR_OPEN __builtin_amdgcn_s_barrier()
// closing barrier: pin so next phase's gloads can't hoist above (buffer-reuse race)
#define BAR_CLOSE do { __builtin_amdgcn_s_barrier(); __builtin_amdgcn_sched_barrier(0); } while (0)
#define LGKM0 do { asm volatile("s_waitcnt lgkmcnt(0)" ::: "memory"); \
                   __builtin_amdgcn_sched_barrier(0); } while (0)

#define LDA_QUAD(qm) do { \
  _Pragma("unroll") for (int mi = 0; mi < 4; mi++) \
  _Pragma("unroll") for (int ks = 0; ks < 2; ks++) { \
    int row = wrr + (qm) * 64 + mi * 16 + li; \
    aA[mi][ks] = *(const s16x8*)&Al[row * 64 + (((ks * 4 + lg) ^ (row & 7)) << 3)]; \
  } } while (0)

#define LDB_QUAD(qn) do { \
  _Pragma("unroll") for (int ni = 0; ni < 2; ni++) \
  _Pragma("unroll") for (int ks = 0; ks < 2; ks++) { \
    int row = wcc + (qn) * 32 + ni * 16 + li; \
    aB[qn][ni][ks] = *(const s16x8*)&Bl[row * 64 + (((ks * 4 + lg) ^ (row & 7)) << 3)]; \
  } } while (0)

#define MMA_QUAD(qm, qn) do { \
  _Pragma("unroll") for (int ks = 0; ks < 2; ks++) \
  _Pragma("unroll") for (int mi = 0; mi < 4; mi++) \
  _Pragma("unroll") for (int ni = 0; ni < 2; ni++) \
    acc[(qm) * 4 + mi][(qn) * 2 + ni] = \
        mfma16(aA[mi][ks], aB[qn][ni][ks], acc[(qm) * 4 + mi][(qn) * 2 + ni]); \
  } while (0)

__global__ void __launch_bounds__(512, 2) k_gemm_qkv(const u16* __restrict__ A,
                                                     const u16* __restrict__ W,
                                                     u16* __restrict__ C) {
  __shared__ u16 SM[2][2][256 * 64];   // [buf][A|B][256 rows x 64 k] = 128 KiB
  const int t = threadIdx.x;
  const int lane = t & 63;
  const int w = t >> 6;
  const int li = lane & 15, lg = lane >> 4;
  const int wr = w >> 2, wc = w & 3;
  const int wrr = wr * 128, wcc = wc * 64;

  const int cpx = gridDim.x >> 3;
  const int swz = (blockIdx.x & 7) * cpx + (blockIdx.x >> 3);
  const int bm = swz / 48, bn = swz - bm * 48;
  const int m0 = bm * 256, n0 = bn * 256;

  const u16* Ag = A + (size_t)m0 * HID;
  const u16* Wg = W + (size_t)n0 * HID;

  fx4 acc[8][4];
#pragma unroll
  for (int i = 0; i < 8; i++)
#pragma unroll
    for (int j = 0; j < 4; j++) acc[i][j] = fx4{0.f, 0.f, 0.f, 0.f};
  s16x8 aA[4][2], aB[2][2][2];

  // ---- prologue: B(0), A(0), B(1) staged; wait for kt=0 resident
  stage_half(Wg, &SM[0][1][0], 0, t);
  stage_half(Wg, &SM[0][1][0], 128, t);
  stage_half(Ag, &SM[0][0][0], 0, t);
  stage_half(Ag, &SM[0][0][0], 128, t);
  stage_half(Wg + 64, &SM[1][1][0], 0, t);
  stage_half(Wg + 64, &SM[1][1][0], 128, t);
  asm volatile("s_waitcnt vmcnt(4)" ::: "memory");
  BAR_CLOSE;

  for (int kt = 0; kt < NKT; kt++) {
    const int cur = kt & 1;
    u16* Al = &SM[cur][0][0];
    u16* Bl = &SM[cur][1][0];
    u16* Anxt = &SM[cur ^ 1][0][0];
    const u16* Agn = Ag + (size_t)(kt + 1) * 64;
    const u16* Wgn = Wg + (size_t)(kt + 2) * 64;

    // ---- phase 0: A-quad0 + B-quad0 reads; stage A(kt+1) half0
    LDA_QUAD(0);
    LDB_QUAD(0);
    if (kt + 1 < NKT) stage_half(Agn, Anxt, 0, t);
    asm volatile("s_waitcnt lgkmcnt(8)" ::: "memory");
    BAR_OPEN;
    LGKM0;
    __builtin_amdgcn_s_setprio(1);
    MMA_QUAD(0, 0);
    __builtin_amdgcn_s_setprio(0);
    BAR_CLOSE;

    // ---- phase 1: B-quad1 reads; stage A(kt+1) half1
    LDB_QUAD(1);
    if (kt + 1 < NKT) stage_half(Agn, Anxt, 128, t);
    BAR_OPEN;
    LGKM0;
    __builtin_amdgcn_s_setprio(1);
    MMA_QUAD(0, 1);
    __builtin_amdgcn_s_setprio(0);
    BAR_CLOSE;

    // ---- phase 2: A-quad1 reads; stage B(kt+2) half0 (cur B is dead after ph1)
    LDA_QUAD(1);
    if (kt + 2 < NKT) stage_half(Wgn, Bl, 0, t);
    BAR_OPEN;
    LGKM0;
    __builtin_amdgcn_s_setprio(1);
    MMA_QUAD(1, 1);
    __builtin_amdgcn_s_setprio(0);
    BAR_CLOSE;

    // ---- phase 3: stage B(kt+2) half1; counted vmcnt
    if (kt + 2 < NKT) stage_half(Wgn, Bl, 128, t);
    BAR_OPEN;
    LGKM0;
    __builtin_amdgcn_s_setprio(1);
    MMA_QUAD(1, 0);
    __builtin_amdgcn_s_setprio(0);
    if (kt + 2 < NKT) {
      asm volatile("s_waitcnt vmcnt(4)" ::: "memory");   // leave B(kt+2) in flight
    } else {
      asm volatile("s_waitcnt vmcnt(0)" ::: "memory");   // tail: drain
    }
    BAR_CLOSE;
  }

  // ---- epilogue: C write (bf16)
#pragma unroll
  for (int mi = 0; mi < 8; mi++)
#pragma unroll
    for (int ni = 0; ni < 4; ni++)
#pragma unroll
      for (int j = 0; j < 4; j++) {
        int r = m0 + wrr + mi * 16 + lg * 4 + j;
        int c = n0 + wcc + ni * 16 + li;
        C[(size_t)r * P3H + c] = f2bf(acc[mi][ni][j]);
      }
}

// ---------------- RoPE: proj -> q,k in [B,NH,S,HD] (bf16) ----------------
__global__ void k_rope(const u16* __restrict__ proj, u16* __restrict__ q,
                       u16* __restrict__ k, const int* __restrict__ pos_ids) {
  int t = blockIdx.x * 256 + threadIdx.x;
  int d = t & 63;
  int h = (t >> 6) & 31;
  int s = (t >> 11) & 2047;
  int b = t >> 22;
  int prow = b * SEQ + s;
  const u16* pr = proj + (size_t)prow * P3H;
  float q1 = bf2f(pr[h * HDIM + d]);
  float q2 = bf2f(pr[h * HDIM + d + 64]);
  float k1 = bf2f(pr[HID + h * HDIM + d]);
  float k2 = bf2f(pr[HID + h * HDIM + d + 64]);
  float p = (float)pos_ids[prow];
  float invf = exp2f(-(float)d * 0.2076205059304601f);
  float ang = p * invf;
  float sn, cs;
  sincosf(ang, &sn, &cs);
  size_t base = ((size_t)(b * NHEAD + h) * SEQ + s) * HDIM + d;
  q[base]      = f2bf(q1 * cs - q2 * sn);
  q[base + 64] = f2bf(q2 * cs + q1 * sn);
  k[base]      = f2bf(k1 * cs - k2 * sn);
  k[base + 64] = f2bf(k2 * cs + k1 * sn);
}

// ---------------- V transpose: proj v-part -> vt [B,NH,HD,S] (bf16) ----------------
__global__ void k_vtrans(const u16* __restrict__ proj, u16* __restrict__ vt) {
  int wid = (blockIdx.x * 256 + threadIdx.x) >> 6;
  int lane = threadIdx.x & 63;
  int half = wid & 1;
  int s8 = (wid >> 1) & 255;
  int h = (wid >> 9) & 31;
  int b = wid >> 14;
  int d = half * 64 + lane;
  int s0 = s8 * 8;
  u16x8 v;
#pragma unroll
  for (int r = 0; r < 8; r++)
    v[r] = proj[(size_t)(b * SEQ + s0 + r) * P3H + 2 * HID + h * HDIM + d];
  *reinterpret_cast<u16x8*>(&vt[((size_t)(b * NHEAD + h) * HDIM + d) * SEQ + s0]) = v;
}

// ---------------- Flash attention (causal), QBLK=128, double-buffered KV ----------------
// block = (b, h, 128 q-rows); 4 waves x 32 rows (2 groups of 16). KV tiles of 64.
// T3/T4: STAGE(t+1) issued before counted vmcnt(8); raw s_barrier (no vmcnt drain).
__device__ __forceinline__ void stage_kv(const u16* __restrict__ kp, const u16* __restrict__ vp,
                                         u16* ksl, u16* vsl, int kv0, int t) {
#pragma unroll
  for (int c = 0; c < 4; c++) {           // K tile 64x128
    int row = c * 16 + (t >> 4);
    int cb = (t & 15) ^ (row & 7);
    gload_lds16(kp + (size_t)(kv0 + row) * HDIM + cb * 8, ksl + (size_t)(c * 256 + t) * 8);
  }
#pragma unroll
  for (int c = 0; c < 4; c++) {           // Vt tile 128x64
    int row = c * 32 + (t >> 3);
    int cb = (t & 7) ^ (row & 7);
    gload_lds16(vp + (size_t)row * SEQ + kv0 + cb * 8, vsl + (size_t)(c * 256 + t) * 8);
  }
}

__global__ void __launch_bounds__(256, 2) k_attn(const u16* __restrict__ q,
                                                 const u16* __restrict__ k,
                                                 const u16* __restrict__ vt,
                                                 float* __restrict__ out) {
  __shared__ u16 Ks[2][64 * 128];   // 32 KB
  __shared__ u16 Vs[2][128 * 64];   // 32 KB
  __shared__ u16 Ps[4][32 * 64];    // 16 KB
  const int t = threadIdx.x;
  const int w = t >> 6, lane = t & 63;
  const int li = lane & 15, lg = lane >> 4;
  const int qb = blockIdx.x;
  const int h = blockIdx.y, b = blockIdx.z;
  const int q0 = qb * 128;
  const int qw = q0 + w * 32;
  const size_t bh = (size_t)(b * NHEAD + h);
  const u16* qp = q + bh * SEQ * HDIM;
  const u16* kp = k + bh * SEQ * HDIM;
  const u16* vp = vt + bh * HDIM * SEQ;

  // Q fragments: group g rows = qw + g*16 + li
  s16x8 aq[2][4];
#pragma unroll
  for (int g = 0; g < 2; g++)
#pragma unroll
    for (int kk = 0; kk < 4; kk++)
      aq[g][kk] = *reinterpret_cast<const s16x8*>(
          &qp[(size_t)(qw + g * 16 + li) * HDIM + kk * 32 + lg * 8]);

  fx4 Oacc[2][8];
#pragma unroll
  for (int g = 0; g < 2; g++)
#pragma unroll
    for (int nd = 0; nd < 8; nd++) Oacc[g][nd] = fx4{0.f, 0.f, 0.f, 0.f};
  float mrun[2][4], lrun[2][4];
#pragma unroll
  for (int g = 0; g < 2; g++)
#pragma unroll
    for (int j = 0; j < 4; j++) { mrun[g][j] = -1e30f; lrun[g][j] = 0.f; }

  const float SC2 = 0.12752551286084110f;       // (1/sqrt(128)) * log2(e)
  const int nt = 2 * (qb + 1);

  stage_kv(kp, vp, Ks[0], Vs[0], 0, t);

  for (int tk = 0; tk < nt; tk++) {
    const int cur = tk & 1;
    if (tk + 1 < nt) {
      stage_kv(kp, vp, Ks[cur ^ 1], Vs[cur ^ 1], (tk + 1) * 64, t);
      asm volatile("s_waitcnt vmcnt(8)" ::: "memory");   // drain tile tk only
    } else {
      asm volatile("s_waitcnt vmcnt(0)" ::: "memory");
    }
    __builtin_amdgcn_s_barrier();

    const u16* Kc = Ks[cur];
    const u16* Vc = Vs[cur];
    const int kv0 = tk * 64;
    const bool diag = (tk >= 2 * qb);

#pragma unroll
    for (int g = 0; g < 2; g++) {
      // ---- QK^T (16 q-rows x 64 kv)
      fx4 sc[4];
      __builtin_amdgcn_s_setprio(1);
#pragma unroll
      for (int n = 0; n < 4; n++) {
        fx4 z = fx4{0.f, 0.f, 0.f, 0.f};
        int r = n * 16 + li;
#pragma unroll
        for (int kk = 0; kk < 4; kk++) {
          s16x8 bk = *reinterpret_cast<const s16x8*>(
              &Kc[r * 128 + (((kk * 4 + lg) ^ (r & 7)) << 3)]);
          z = mfma16(aq[g][kk], bk, z);
        }
        sc[n] = z;
      }
      __builtin_amdgcn_s_setprio(0);
      // ---- scale + causal mask
#pragma unroll
      for (int n = 0; n < 4; n++)
#pragma unroll
        for (int j = 0; j < 4; j++) {
          float sv = sc[n][j] * SC2;
          if (diag) {
            int kvg = kv0 + n * 16 + li;
            int qg = qw + g * 16 + lg * 4 + j;
            if (kvg > qg) sv = -1e30f;
          }
          sc[n][j] = sv;
        }
      // ---- row max + defer-max rescale (T13, THR=8 in exp2 domain)
      float nm[4];
      int big = 0;
#pragma unroll
      for (int j = 0; j < 4; j++) {
        float mv = fmaxf(fmaxf(sc[0][j], sc[1][j]), fmaxf(sc[2][j], sc[3][j]));
        mv = fmaxf(mv, __shfl_xor(mv, 1));
        mv = fmaxf(mv, __shfl_xor(mv, 2));
        mv = fmaxf(mv, __shfl_xor(mv, 4));
        mv = fmaxf(mv, __shfl_xor(mv, 8));
        nm[j] = mv;
        big |= (mv > mrun[g][j] + 8.f) ? 1 : 0;
      }
      if (__any(big)) {
#pragma unroll
        for (int j = 0; j < 4; j++) {
          float mnew = fmaxf(mrun[g][j], nm[j]);
          float al = exp2f(mrun[g][j] - mnew);
          mrun[g][j] = mnew;
          lrun[g][j] *= al;
#pragma unroll
          for (int nd = 0; nd < 8; nd++) Oacc[g][nd][j] *= al;
        }
      }
      // ---- P = exp2(s - m), write swizzled LDS, row sums
      float rsum[4] = {0.f, 0.f, 0.f, 0.f};
#pragma unroll
      for (int n = 0; n < 4; n++)
#pragma unroll
        for (int j = 0; j < 4; j++) {
          float pv = exp2f(sc[n][j] - mrun[g][j]);
          rsum[j] += pv;
          int row = g * 16 + lg * 4 + j;
          int blk = (n * 2 + (li >> 3)) ^ (row & 7);
          Ps[w][row * 64 + (blk << 3) + (li & 7)] = f2bf(pv);
        }
#pragma unroll
      for (int j = 0; j < 4; j++) {
        float rv = rsum[j];
        rv += __shfl_xor(rv, 1);
        rv += __shfl_xor(rv, 2);
        rv += __shfl_xor(rv, 4);
        rv += __shfl_xor(rv, 8);
        lrun[g][j] += rv;
      }
      // ---- O += P V
      s16x8 ap[2];
#pragma unroll
      for (int kvc = 0; kvc < 2; kvc++) {
        int prow = g * 16 + li;
        ap[kvc] = *reinterpret_cast<const s16x8*>(
            &Ps[w][prow * 64 + (((kvc * 4 + lg) ^ (prow & 7)) << 3)]);
      }
      __builtin_amdgcn_s_setprio(1);
#pragma unroll
      for (int nd = 0; nd < 8; nd++) {
        int dr = nd * 16 + li;
#pragma unroll
        for (int kvc = 0; kvc < 2; kvc++) {
          s16x8 bv = *reinterpret_cast<const s16x8*>(
              &Vc[dr * 64 + (((kvc * 4 + lg) ^ (dr & 7)) << 3)]);
          Oacc[g][nd] = mfma16(ap[kvc], bv, Oacc[g][nd]);
        }
      }
      __builtin_amdgcn_s_setprio(0);
    }
    __builtin_amdgcn_s_barrier();
    __builtin_amdgcn_sched_barrier(0);   // keep next iter's STAGE below this barrier
  }

  // ---- epilogue
#pragma unroll
  for (int g = 0; g < 2; g++)
#pragma unroll
    for (int j = 0; j < 4; j++) {
      float rl = 1.0f / lrun[g][j];
      int s = qw + g * 16 + lg * 4 + j;
      float* op = out + ((size_t)(b * SEQ) + s) * HID + h * HDIM;
#pragma unroll
      for (int nd = 0; nd < 8; nd++) op[nd * 16 + li] = Oacc[g][nd][j] * rl;
    }
}

extern "C" void kernel_launch(void* const* d_in, const int* in_sizes, int n_in,
                              void* d_out, int out_size, void* d_ws, size_t ws_size,
                              hipStream_t stream) {
  const float* hidden = (const float*)d_in[0];
  const float* wpack = (const float*)d_in[1];
  const int* pos = (const int*)d_in[3];
  float* out = (float*)d_out;

  char* ws = (char*)d_ws;
  u16* hid_bf = (u16*)ws;
  u16* wp_bf = (u16*)(ws + ((size_t)32 << 20));
  u16* qb = (u16*)ws;
  u16* kb = (u16*)(ws + ((size_t)32 << 20));
  u16* vtb = (u16*)(ws + ((size_t)64 << 20));
  u16* proj = (u16*)(ws + ((size_t)128 << 20));

  k_cvt<<<(HID * HID / 4 + 255) / 256, 256, 0, stream>>>(hidden, hid_bf, HID * HID / 4);
  k_cvt<<<(P3H * HID / 4 + 255) / 256, 256, 0, stream>>>(wpack, wp_bf, P3H * HID / 4);

  k_gemm_qkv<<<768, 512, 0, stream>>>(hid_bf, wp_bf, proj);

  k_rope<<<(2 * SEQ * NHEAD * 64) / 256, 256, 0, stream>>>(proj, qb, kb, pos);
  k_vtrans<<<(2 * NHEAD * (SEQ / 8) * 2) / 4, 256, 0, stream>>>(proj, vtb);

  dim3 ga(SEQ / 128, NHEAD, 2);
  k_attn<<<ga, 256, 0, stream>>>(qb, kb, vtb, out);
}

// Round 4
// 695.631 us; speedup vs baseline: 1.2480x; 1.0798x over previous
//
#include <hip/hip_runtime.h>
#include <stdint.h>

typedef unsigned short u16;
typedef __attribute__((ext_vector_type(8))) short s16x8;
typedef __attribute__((ext_vector_type(8))) unsigned short u16x8;
typedef __attribute__((ext_vector_type(4))) unsigned short u16x4;
typedef __attribute__((ext_vector_type(4))) float fx4;
typedef __bf16 bf16x8 __attribute__((ext_vector_type(8)));

#define SEQ 2048
#define HID 4096
#define NHEAD 32
#define HDIM 128
#define P3H 12288
#define NKT 64  // K-tiles of 64 in the GEMM (4096/64)

__device__ __forceinline__ u16 f2bf(float f) {
  unsigned u = __builtin_bit_cast(unsigned, f);
  u += 0x7fffu + ((u >> 16) & 1u);          // RNE
  return (u16)(u >> 16);
}
__device__ __forceinline__ float bf2f(u16 h) {
  unsigned u = ((unsigned)h) << 16;
  return __builtin_bit_cast(float, u);
}
__device__ __forceinline__ void gload_lds16(const void* g, void* l) {
  __builtin_amdgcn_global_load_lds((const __attribute__((address_space(1))) void*)g,
                                   (__attribute__((address_space(3))) void*)l, 16, 0, 0);
}
__device__ __forceinline__ fx4 mfma16(s16x8 a, s16x8 b, fx4 c) {
  return __builtin_amdgcn_mfma_f32_16x16x32_bf16(
      __builtin_bit_cast(bf16x8, a), __builtin_bit_cast(bf16x8, b), c, 0, 0, 0);
}

// ---------------- f32 -> bf16 convert ----------------
__global__ void k_cvt(const float* __restrict__ src, u16* __restrict__ dst, int n4) {
  int i = blockIdx.x * blockDim.x + threadIdx.x;
  if (i >= n4) return;
  float4 v = reinterpret_cast<const float4*>(src)[i];
  u16x4 o;
  o[0] = f2bf(v.x); o[1] = f2bf(v.y); o[2] = f2bf(v.z); o[3] = f2bf(v.w);
  reinterpret_cast<u16x4*>(dst)[i] = o;
}

// ---------------- QKV GEMM: 256x256 8-phase template ----------------
__device__ __forceinline__ void stage_half(const u16* __restrict__ g, u16* l, int r0, int t) {
#pragma unroll
  for (int c = 0; c < 2; c++) {
    int row = r0 + c * 64 + (t >> 3);
    int blk = (t & 7) ^ ((t >> 3) & 7);
    gload_lds16(g + (size_t)row * HID + blk * 8, l + row * 64 + (t & 7) * 8);
  }
}

#define BAR_OPEN __builtin_amdgcn_s_barrier()
#define BAR_CLOSE do { __builtin_amdgcn_s_barrier(); __builtin_amdgcn_sched_barrier(0); } while (0)
#define LGKM0 do { asm volatile("s_waitcnt lgkmcnt(0)" ::: "memory"); \
                   __builtin_amdgcn_sched_barrier(0); } while (0)

#define LDA_QUAD(qm) do { \
  _Pragma("unroll") for (int mi = 0; mi < 4; mi++) \
  _Pragma("unroll") for (int ks = 0; ks < 2; ks++) { \
    int row = wrr + (qm) * 64 + mi * 16 + li; \
    aA[mi][ks] = *(const s16x8*)&Al[row * 64 + (((ks * 4 + lg) ^ (row & 7)) << 3)]; \
  } } while (0)

#define LDB_QUAD(qn) do { \
  _Pragma("unroll") for (int ni = 0; ni < 2; ni++) \
  _Pragma("unroll") for (int ks = 0; ks < 2; ks++) { \
    int row = wcc + (qn) * 32 + ni * 16 + li; \
    aB[qn][ni][ks] = *(const s16x8*)&Bl[row * 64 + (((ks * 4 + lg) ^ (row & 7)) << 3)]; \
  } } while (0)

#define MMA_QUAD(qm, qn) do { \
  _Pragma("unroll") for (int ks = 0; ks < 2; ks++) \
  _Pragma("unroll") for (int mi = 0; mi < 4; mi++) \
  _Pragma("unroll") for (int ni = 0; ni < 2; ni++) \
    acc[(qm) * 4 + mi][(qn) * 2 + ni] = \
        mfma16(aA[mi][ks], aB[qn][ni][ks], acc[(qm) * 4 + mi][(qn) * 2 + ni]); \
  } while (0)

__global__ void __launch_bounds__(512, 2) k_gemm_qkv(const u16* __restrict__ A,
                                                     const u16* __restrict__ W,
                                                     u16* __restrict__ C) {
  __shared__ u16 SM[2][2][256 * 64];   // [buf][A|B][256 rows x 64 k] = 128 KiB
  const int t = threadIdx.x;
  const int lane = t & 63;
  const int w = t >> 6;
  const int li = lane & 15, lg = lane >> 4;
  const int wr = w >> 2, wc = w & 3;
  const int wrr = wr * 128, wcc = wc * 64;

  const int cpx = gridDim.x >> 3;
  const int swz = (blockIdx.x & 7) * cpx + (blockIdx.x >> 3);
  const int bm = swz / 48, bn = swz - bm * 48;
  const int m0 = bm * 256, n0 = bn * 256;

  const u16* Ag = A + (size_t)m0 * HID;
  const u16* Wg = W + (size_t)n0 * HID;

  fx4 acc[8][4];
#pragma unroll
  for (int i = 0; i < 8; i++)
#pragma unroll
    for (int j = 0; j < 4; j++) acc[i][j] = fx4{0.f, 0.f, 0.f, 0.f};
  s16x8 aA[4][2], aB[2][2][2];

  stage_half(Wg, &SM[0][1][0], 0, t);
  stage_half(Wg, &SM[0][1][0], 128, t);
  stage_half(Ag, &SM[0][0][0], 0, t);
  stage_half(Ag, &SM[0][0][0], 128, t);
  stage_half(Wg + 64, &SM[1][1][0], 0, t);
  stage_half(Wg + 64, &SM[1][1][0], 128, t);
  asm volatile("s_waitcnt vmcnt(4)" ::: "memory");
  BAR_CLOSE;

  for (int kt = 0; kt < NKT; kt++) {
    const int cur = kt & 1;
    u16* Al = &SM[cur][0][0];
    u16* Bl = &SM[cur][1][0];
    u16* Anxt = &SM[cur ^ 1][0][0];
    const u16* Agn = Ag + (size_t)(kt + 1) * 64;
    const u16* Wgn = Wg + (size_t)(kt + 2) * 64;

    LDA_QUAD(0);
    LDB_QUAD(0);
    if (kt + 1 < NKT) stage_half(Agn, Anxt, 0, t);
    asm volatile("s_waitcnt lgkmcnt(8)" ::: "memory");
    BAR_OPEN;
    LGKM0;
    __builtin_amdgcn_s_setprio(1);
    MMA_QUAD(0, 0);
    __builtin_amdgcn_s_setprio(0);
    BAR_CLOSE;

    LDB_QUAD(1);
    if (kt + 1 < NKT) stage_half(Agn, Anxt, 128, t);
    BAR_OPEN;
    LGKM0;
    __builtin_amdgcn_s_setprio(1);
    MMA_QUAD(0, 1);
    __builtin_amdgcn_s_setprio(0);
    BAR_CLOSE;

    LDA_QUAD(1);
    if (kt + 2 < NKT) stage_half(Wgn, Bl, 0, t);
    BAR_OPEN;
    LGKM0;
    __builtin_amdgcn_s_setprio(1);
    MMA_QUAD(1, 1);
    __builtin_amdgcn_s_setprio(0);
    BAR_CLOSE;

    if (kt + 2 < NKT) stage_half(Wgn, Bl, 128, t);
    BAR_OPEN;
    LGKM0;
    __builtin_amdgcn_s_setprio(1);
    MMA_QUAD(1, 0);
    __builtin_amdgcn_s_setprio(0);
    if (kt + 2 < NKT) {
      asm volatile("s_waitcnt vmcnt(4)" ::: "memory");
    } else {
      asm volatile("s_waitcnt vmcnt(0)" ::: "memory");
    }
    BAR_CLOSE;
  }

#pragma unroll
  for (int mi = 0; mi < 8; mi++)
#pragma unroll
    for (int ni = 0; ni < 4; ni++)
#pragma unroll
      for (int j = 0; j < 4; j++) {
        int r = m0 + wrr + mi * 16 + lg * 4 + j;
        int c = n0 + wcc + ni * 16 + li;
        C[(size_t)r * P3H + c] = f2bf(acc[mi][ni][j]);
      }
}

// ---------------- RoPE: proj -> q,k in [B,NH,S,HD] (bf16) ----------------
__global__ void k_rope(const u16* __restrict__ proj, u16* __restrict__ q,
                       u16* __restrict__ k, const int* __restrict__ pos_ids) {
  int t = blockIdx.x * 256 + threadIdx.x;
  int d = t & 63;
  int h = (t >> 6) & 31;
  int s = (t >> 11) & 2047;
  int b = t >> 22;
  int prow = b * SEQ + s;
  const u16* pr = proj + (size_t)prow * P3H;
  float q1 = bf2f(pr[h * HDIM + d]);
  float q2 = bf2f(pr[h * HDIM + d + 64]);
  float k1 = bf2f(pr[HID + h * HDIM + d]);
  float k2 = bf2f(pr[HID + h * HDIM + d + 64]);
  float p = (float)pos_ids[prow];
  float invf = exp2f(-(float)d * 0.2076205059304601f);
  float ang = p * invf;
  float sn, cs;
  sincosf(ang, &sn, &cs);
  size_t base = ((size_t)(b * NHEAD + h) * SEQ + s) * HDIM + d;
  q[base]      = f2bf(q1 * cs - q2 * sn);
  q[base + 64] = f2bf(q2 * cs + q1 * sn);
  k[base]      = f2bf(k1 * cs - k2 * sn);
  k[base + 64] = f2bf(k2 * cs + k1 * sn);
}

// ---------------- V transpose: proj v-part -> vt [B,NH,HD,S] (bf16) ----------------
__global__ void k_vtrans(const u16* __restrict__ proj, u16* __restrict__ vt) {
  int wid = (blockIdx.x * 256 + threadIdx.x) >> 6;
  int lane = threadIdx.x & 63;
  int half = wid & 1;
  int s8 = (wid >> 1) & 255;
  int h = (wid >> 9) & 31;
  int b = wid >> 14;
  int d = half * 64 + lane;
  int s0 = s8 * 8;
  u16x8 v;
#pragma unroll
  for (int r = 0; r < 8; r++)
    v[r] = proj[(size_t)(b * SEQ + s0 + r) * P3H + 2 * HID + h * HDIM + d];
  *reinterpret_cast<u16x8*>(&vt[((size_t)(b * NHEAD + h) * HDIM + d) * SEQ + s0]) = v;
}

// ---------------- Flash attention (causal), swapped-QK^T softmax ----------------
// block = (b, h, 128 q-rows); 4 waves x 32 rows (2 groups of 16). KV tiles of 64,
// double-buffered with counted vmcnt. QK^T computed as S^T = mfma(K,Q) so each
// lane holds 16 scores of ONE q-row (q = lane&15): row reductions are in-lane
// trees + 2 shfl_xor (vs depth-4 chains x8). P packed to LDS via 4 ds_write_b64.
__device__ __forceinline__ void stage_kv(const u16* __restrict__ kp, const u16* __restrict__ vp,
                                         u16* ksl, u16* vsl, int kv0, int t) {
#pragma unroll
  for (int c = 0; c < 4; c++) {           // K tile 64x128
    int row = c * 16 + (t >> 4);
    int cb = (t & 15) ^ (row & 7);
    gload_lds16(kp + (size_t)(kv0 + row) * HDIM + cb * 8, ksl + (size_t)(c * 256 + t) * 8);
  }
#pragma unroll
  for (int c = 0; c < 4; c++) {           // Vt tile 128x64
    int row = c * 32 + (t >> 3);
    int cb = (t & 7) ^ (row & 7);
    gload_lds16(vp + (size_t)row * SEQ + kv0 + cb * 8, vsl + (size_t)(c * 256 + t) * 8);
  }
}

__global__ void __launch_bounds__(256, 2) k_attn(const u16* __restrict__ q,
                                                 const u16* __restrict__ k,
                                                 const u16* __restrict__ vt,
                                                 float* __restrict__ out) {
  __shared__ u16 Ks[2][64 * 128];   // 32 KB
  __shared__ u16 Vs[2][128 * 64];   // 32 KB
  __shared__ u16 Ps[4][16 * 64];    // 8 KB (per-wave P tile, 16 q x 64 kv)
  const int t = threadIdx.x;
  const int w = t >> 6, lane = t & 63;
  const int li = lane & 15, lg = lane >> 4;
  const int qb = gridDim.x - 1 - blockIdx.x;   // heavy diagonal blocks first
  const int h = blockIdx.y, b = blockIdx.z;
  const int q0 = qb * 128;
  const int qw = q0 + w * 32;
  const size_t bh = (size_t)(b * NHEAD + h);
  const u16* qp = q + bh * SEQ * HDIM;
  const u16* kp = k + bh * SEQ * HDIM;
  const u16* vp = vt + bh * HDIM * SEQ;

  // Q fragments (B-operand for swapped QK^T): lane li = q-row
  s16x8 bq[2][4];
#pragma unroll
  for (int g = 0; g < 2; g++)
#pragma unroll
    for (int kk = 0; kk < 4; kk++)
      bq[g][kk] = *reinterpret_cast<const s16x8*>(
          &qp[(size_t)(qw + g * 16 + li) * HDIM + kk * 32 + lg * 8]);

  fx4 Oacc[2][8];
#pragma unroll
  for (int g = 0; g < 2; g++)
#pragma unroll
    for (int nd = 0; nd < 8; nd++) Oacc[g][nd] = fx4{0.f, 0.f, 0.f, 0.f};
  // per-lane running max/sum for q-row (qw + g*16 + li)
  float mrun[2] = {-1e30f, -1e30f}, lrun[2] = {0.f, 0.f};

  const float SC2 = 0.12752551286084110f;       // (1/sqrt(128)) * log2(e)
  const int nt = 2 * (qb + 1);
  const int psw = (li & 7) << 4;                // P swizzle byte mask

  stage_kv(kp, vp, Ks[0], Vs[0], 0, t);

  for (int tk = 0; tk < nt; tk++) {
    const int cur = tk & 1;
    if (tk + 1 < nt) {
      stage_kv(kp, vp, Ks[cur ^ 1], Vs[cur ^ 1], (tk + 1) * 64, t);
      asm volatile("s_waitcnt vmcnt(8)" ::: "memory");   // drain tile tk only
    } else {
      asm volatile("s_waitcnt vmcnt(0)" ::: "memory");
    }
    __builtin_amdgcn_s_barrier();

    const u16* Kc = Ks[cur];
    const u16* Vc = Vs[cur];
    const int kv0 = tk * 64;
    const bool diag = (tk >= 2 * qb);

#pragma unroll
    for (int g = 0; g < 2; g++) {
      // ---- S^T = K Q^T : rows = kv (lg*4+j), cols = q (li)
      fx4 sc[4];
      __builtin_amdgcn_s_setprio(1);
#pragma unroll
      for (int n = 0; n < 4; n++) {
        fx4 z = fx4{0.f, 0.f, 0.f, 0.f};
        int r = n * 16 + li;
#pragma unroll
        for (int kk = 0; kk < 4; kk++) {
          s16x8 ak = *reinterpret_cast<const s16x8*>(
              &Kc[r * 128 + (((kk * 4 + lg) ^ (r & 7)) << 3)]);
          z = mfma16(ak, bq[g][kk], z);
        }
        sc[n] = z;
      }
      __builtin_amdgcn_s_setprio(0);
      // ---- scale + causal mask (lane q = qw+g*16+li; kv = kv0+n*16+lg*4+j)
      const int qg = qw + g * 16 + li;
#pragma unroll
      for (int n = 0; n < 4; n++)
#pragma unroll
        for (int j = 0; j < 4; j++) {
          float sv = sc[n][j] * SC2;
          if (diag) {
            int kvg = kv0 + n * 16 + lg * 4 + j;
            if (kvg > qg) sv = -1e30f;
          }
          sc[n][j] = sv;
        }
      // ---- in-lane max tree + 2-shfl cross-group reduce
      float mn[4];
#pragma unroll
      for (int n = 0; n < 4; n++)
        mn[n] = fmaxf(fmaxf(sc[n][0], sc[n][1]), fmaxf(sc[n][2], sc[n][3]));
      float vmax = fmaxf(fmaxf(mn[0], mn[1]), fmaxf(mn[2], mn[3]));
      vmax = fmaxf(vmax, __shfl_xor(vmax, 16));
      vmax = fmaxf(vmax, __shfl_xor(vmax, 32));
      // ---- defer-max (T13, THR=8 in exp2 domain)
      if (__any(vmax > mrun[g] + 8.f)) {
        float mnew = fmaxf(mrun[g], vmax);
        float al = exp2f(mrun[g] - mnew);
        mrun[g] = mnew;
        lrun[g] *= al;
        // redistribute alpha to (lg,j) output-row layout
        float alj[4];
#pragma unroll
        for (int j = 0; j < 4; j++) alj[j] = __shfl(al, lg * 4 + j);
#pragma unroll
        for (int nd = 0; nd < 8; nd++)
#pragma unroll
          for (int j = 0; j < 4; j++) Oacc[g][nd][j] *= alj[j];
      }
      // ---- P = exp2(s - m); in-lane sum tree; pack + swizzled b64 store
      float ps[4];
#pragma unroll
      for (int n = 0; n < 4; n++) {
        u16x4 pk;
#pragma unroll
        for (int j = 0; j < 4; j++) {
          float pv = exp2f(sc[n][j] - mrun[g]);
          sc[n][j] = pv;
          pk[j] = f2bf(pv);
        }
        ps[n] = (sc[n][0] + sc[n][1]) + (sc[n][2] + sc[n][3]);
        *reinterpret_cast<u16x4*>(
            &Ps[w][li * 64 + (((n * 32 + lg * 8) ^ psw) >> 1)]) = pk;
      }
      float psum = (ps[0] + ps[1]) + (ps[2] + ps[3]);
      psum += __shfl_xor(psum, 16);
      psum += __shfl_xor(psum, 32);
      lrun[g] += psum;
      // ---- O += P V  (A = P rows q=li from Ps, B = V from swizzled Vt_lds)
      s16x8 ap[2];
#pragma unroll
      for (int kvc = 0; kvc < 2; kvc++)
        ap[kvc] = *reinterpret_cast<const s16x8*>(
            &Ps[w][li * 64 + (((kvc * 64 + lg * 16) ^ psw) >> 1)]);
      __builtin_amdgcn_s_setprio(1);
#pragma unroll
      for (int nd = 0; nd < 8; nd++) {
        int dr = nd * 16 + li;
#pragma unroll
        for (int kvc = 0; kvc < 2; kvc++) {
          s16x8 bv = *reinterpret_cast<const s16x8*>(
              &Vc[dr * 64 + (((kvc * 4 + lg) ^ (dr & 7)) << 3)]);
          Oacc[g][nd] = mfma16(ap[kvc], bv, Oacc[g][nd]);
        }
      }
      __builtin_amdgcn_s_setprio(0);
    }
    __builtin_amdgcn_s_barrier();
    __builtin_amdgcn_sched_barrier(0);   // keep next iter's STAGE below this barrier
  }

  // ---- epilogue: fetch lrun for output rows (lg,j) via shfl, normalize, store
#pragma unroll
  for (int g = 0; g < 2; g++)
#pragma unroll
    for (int j = 0; j < 4; j++) {
      float rl = 1.0f / __shfl(lrun[g], lg * 4 + j);
      int s = qw + g * 16 + lg * 4 + j;
      float* op = out + ((size_t)(b * SEQ) + s) * HID + h * HDIM;
#pragma unroll
      for (int nd = 0; nd < 8; nd++) op[nd * 16 + li] = Oacc[g][nd][j] * rl;
    }
}

extern "C" void kernel_launch(void* const* d_in, const int* in_sizes, int n_in,
                              void* d_out, int out_size, void* d_ws, size_t ws_size,
                              hipStream_t stream) {
  const float* hidden = (const float*)d_in[0];
  const float* wpack = (const float*)d_in[1];
  const int* pos = (const int*)d_in[3];
  float* out = (float*)d_out;

  char* ws = (char*)d_ws;
  u16* hid_bf = (u16*)ws;
  u16* wp_bf = (u16*)(ws + ((size_t)32 << 20));
  u16* qb = (u16*)ws;
  u16* kb = (u16*)(ws + ((size_t)32 << 20));
  u16* vtb = (u16*)(ws + ((size_t)64 << 20));
  u16* proj = (u16*)(ws + ((size_t)128 << 20));

  k_cvt<<<(HID * HID / 4 + 255) / 256, 256, 0, stream>>>(hidden, hid_bf, HID * HID / 4);
  k_cvt<<<(P3H * HID / 4 + 255) / 256, 256, 0, stream>>>(wpack, wp_bf, P3H * HID / 4);

  k_gemm_qkv<<<768, 512, 0, stream>>>(hid_bf, wp_bf, proj);

  k_rope<<<(2 * SEQ * NHEAD * 64) / 256, 256, 0, stream>>>(proj, qb, kb, pos);
  k_vtrans<<<(2 * NHEAD * (SEQ / 8) * 2) / 4, 256, 0, stream>>>(proj, vtb);

  dim3 ga(SEQ / 128, NHEAD, 2);
  k_attn<<<ga, 256, 0, stream>>>(qb, kb, vtb, out);
}

// Round 5
// 645.656 us; speedup vs baseline: 1.3446x; 1.0774x over previous
//
#include <hip/hip_runtime.h>
#include <hip/hip_bf16.h>
#include <stdint.h>

typedef unsigned short u16;
typedef __attribute__((ext_vector_type(8))) short s16x8;
typedef __attribute__((ext_vector_type(8))) unsigned short u16x8;
typedef __attribute__((ext_vector_type(4))) unsigned short u16x4;
typedef __attribute__((ext_vector_type(4))) float fx4;
typedef __bf16 bf16x8 __attribute__((ext_vector_type(8)));

#define SEQ 2048
#define HID 4096
#define NHEAD 32
#define HDIM 128
#define P3H 12288
#define NKT 64  // K-tiles of 64 in the GEMM (4096/64)

__device__ __forceinline__ u16 f2bf(float f) {
  unsigned u = __builtin_bit_cast(unsigned, f);
  u += 0x7fffu + ((u >> 16) & 1u);          // RNE
  return (u16)(u >> 16);
}
__device__ __forceinline__ float bf2f(u16 h) {
  unsigned u = ((unsigned)h) << 16;
  return __builtin_bit_cast(float, u);
}
__device__ __forceinline__ void gload_lds16(const void* g, void* l) {
  __builtin_amdgcn_global_load_lds((const __attribute__((address_space(1))) void*)g,
                                   (__attribute__((address_space(3))) void*)l, 16, 0, 0);
}
__device__ __forceinline__ fx4 mfma16(s16x8 a, s16x8 b, fx4 c) {
  return __builtin_amdgcn_mfma_f32_16x16x32_bf16(
      __builtin_bit_cast(bf16x8, a), __builtin_bit_cast(bf16x8, b), c, 0, 0, 0);
}

// ---------------- f32 -> bf16 convert ----------------
__global__ void k_cvt(const float* __restrict__ src, u16* __restrict__ dst, int n4) {
  int i = blockIdx.x * blockDim.x + threadIdx.x;
  if (i >= n4) return;
  float4 v = reinterpret_cast<const float4*>(src)[i];
  u16x4 o;
  o[0] = f2bf(v.x); o[1] = f2bf(v.y); o[2] = f2bf(v.z); o[3] = f2bf(v.w);
  reinterpret_cast<u16x4*>(dst)[i] = o;
}

// ---------------- QKV GEMM: 256x256 8-phase template, 3-half-tile prefetch ----------------
__device__ __forceinline__ void stage_half(const u16* __restrict__ g, u16* l, int r0, int t) {
#pragma unroll
  for (int c = 0; c < 2; c++) {
    int row = r0 + c * 64 + (t >> 3);
    int blk = (t & 7) ^ ((t >> 3) & 7);
    gload_lds16(g + (size_t)row * HID + blk * 8, l + row * 64 + (t & 7) * 8);
  }
}

#define BAR_OPEN __builtin_amdgcn_s_barrier()
#define BAR_CLOSE do { __builtin_amdgcn_s_barrier(); __builtin_amdgcn_sched_barrier(0); } while (0)
#define LGKM0 do { asm volatile("s_waitcnt lgkmcnt(0)" ::: "memory"); \
                   __builtin_amdgcn_sched_barrier(0); } while (0)

#define LDA_QUAD(qm) do { \
  _Pragma("unroll") for (int mi = 0; mi < 4; mi++) \
  _Pragma("unroll") for (int ks = 0; ks < 2; ks++) { \
    int row = wrr + (qm) * 64 + mi * 16 + li; \
    aA[mi][ks] = *(const s16x8*)&Al[row * 64 + (((ks * 4 + lg) ^ (row & 7)) << 3)]; \
  } } while (0)

#define LDB_QUAD(qn) do { \
  _Pragma("unroll") for (int ni = 0; ni < 2; ni++) \
  _Pragma("unroll") for (int ks = 0; ks < 2; ks++) { \
    int row = wcc + (qn) * 32 + ni * 16 + li; \
    aB[qn][ni][ks] = *(const s16x8*)&Bl[row * 64 + (((ks * 4 + lg) ^ (row & 7)) << 3)]; \
  } } while (0)

#define MMA_QUAD(qm, qn) do { \
  _Pragma("unroll") for (int ks = 0; ks < 2; ks++) \
  _Pragma("unroll") for (int mi = 0; mi < 4; mi++) \
  _Pragma("unroll") for (int ni = 0; ni < 2; ni++) \
    acc[(qm) * 4 + mi][(qn) * 2 + ni] = \
        mfma16(aA[mi][ks], aB[qn][ni][ks], acc[(qm) * 4 + mi][(qn) * 2 + ni]); \
  } while (0)

__global__ void __launch_bounds__(512, 2) k_gemm_qkv(const u16* __restrict__ A,
                                                     const u16* __restrict__ W,
                                                     u16* __restrict__ C) {
  __shared__ u16 SM[2][2][256 * 64];   // [buf][A|B][256 rows x 64 k] = 128 KiB
  const int t = threadIdx.x;
  const int lane = t & 63;
  const int w = t >> 6;
  const int li = lane & 15, lg = lane >> 4;
  const int wr = w >> 2, wc = w & 3;
  const int wrr = wr * 128, wcc = wc * 64;

  const int cpx = gridDim.x >> 3;
  const int swz = (blockIdx.x & 7) * cpx + (blockIdx.x >> 3);
  const int bm = swz / 48, bn = swz - bm * 48;
  const int m0 = bm * 256, n0 = bn * 256;

  const u16* Ag = A + (size_t)m0 * HID;
  const u16* Wg = W + (size_t)n0 * HID;

  fx4 acc[8][4];
#pragma unroll
  for (int i = 0; i < 8; i++)
#pragma unroll
    for (int j = 0; j < 4; j++) acc[i][j] = fx4{0.f, 0.f, 0.f, 0.f};
  s16x8 aA[4][2], aB[2][2][2];

  // ---- prologue: A0, B0 (oldest), then B1, A1h0; vmcnt(6) drains A0,B0
  stage_half(Ag, &SM[0][0][0], 0, t);
  stage_half(Ag, &SM[0][0][0], 128, t);
  stage_half(Wg, &SM[0][1][0], 0, t);
  stage_half(Wg, &SM[0][1][0], 128, t);
  stage_half(Wg + 64, &SM[1][1][0], 0, t);
  stage_half(Wg + 64, &SM[1][1][0], 128, t);
  stage_half(Ag + 64, &SM[1][0][0], 0, t);
  asm volatile("s_waitcnt vmcnt(6)" ::: "memory");
  BAR_CLOSE;

  for (int kt = 0; kt < NKT; kt++) {
    const int cur = kt & 1;
    u16* Al = &SM[cur][0][0];
    u16* Bl = &SM[cur][1][0];
    u16* Anxt = &SM[cur ^ 1][0][0];
    const u16* Ag1 = Ag + (size_t)(kt + 1) * 64;   // A(kt+1)
    const u16* Ag2 = Ag + (size_t)(kt + 2) * 64;   // A(kt+2)
    const u16* Wg2 = Wg + (size_t)(kt + 2) * 64;   // B(kt+2)

    // ---- phase 0: A-quad0 + B-quad0 reads; stage A(kt+1) half1 (h0 staged last kt)
    LDA_QUAD(0);
    LDB_QUAD(0);
    if (kt + 1 < NKT) stage_half(Ag1, Anxt, 128, t);
    asm volatile("s_waitcnt lgkmcnt(8)" ::: "memory");
    BAR_OPEN;
    LGKM0;
    __builtin_amdgcn_s_setprio(1);
    MMA_QUAD(0, 0);
    __builtin_amdgcn_s_setprio(0);
    BAR_CLOSE;

    // ---- phase 1: B-quad1 reads (last B(kt) use)
    LDB_QUAD(1);
    BAR_OPEN;
    LGKM0;
    __builtin_amdgcn_s_setprio(1);
    MMA_QUAD(0, 1);
    __builtin_amdgcn_s_setprio(0);
    BAR_CLOSE;

    // ---- phase 2: A-quad1 reads (last A(kt) use); stage B(kt+2) half0
    LDA_QUAD(1);
    if (kt + 2 < NKT) stage_half(Wg2, Bl, 0, t);
    BAR_OPEN;
    LGKM0;
    __builtin_amdgcn_s_setprio(1);
    MMA_QUAD(1, 1);
    __builtin_amdgcn_s_setprio(0);
    BAR_CLOSE;

    // ---- phase 3: stage B(kt+2) half1 + A(kt+2) half0; counted vmcnt(6)
    if (kt + 2 < NKT) {
      stage_half(Wg2, Bl, 128, t);
      stage_half(Ag2, Al, 0, t);
    }
    BAR_OPEN;
    LGKM0;
    __builtin_amdgcn_s_setprio(1);
    MMA_QUAD(1, 0);
    __builtin_amdgcn_s_setprio(0);
    if (kt + 2 < NKT) {
      asm volatile("s_waitcnt vmcnt(6)" ::: "memory");   // 3 half-tiles stay in flight
    } else {
      asm volatile("s_waitcnt vmcnt(0)" ::: "memory");   // tail: drain
    }
    BAR_CLOSE;
  }

  // ---- epilogue: C write (bf16)
#pragma unroll
  for (int mi = 0; mi < 8; mi++)
#pragma unroll
    for (int ni = 0; ni < 4; ni++)
#pragma unroll
      for (int j = 0; j < 4; j++) {
        int r = m0 + wrr + mi * 16 + lg * 4 + j;
        int c = n0 + wcc + ni * 16 + li;
        C[(size_t)r * P3H + c] = f2bf(acc[mi][ni][j]);
      }
}

// ---------------- RoPE: proj -> q,k in [B,NH,S,HD] (bf16) ----------------
__global__ void k_rope(const u16* __restrict__ proj, u16* __restrict__ q,
                       u16* __restrict__ k, const int* __restrict__ pos_ids) {
  int t = blockIdx.x * 256 + threadIdx.x;
  int d = t & 63;
  int h = (t >> 6) & 31;
  int s = (t >> 11) & 2047;
  int b = t >> 22;
  int prow = b * SEQ + s;
  const u16* pr = proj + (size_t)prow * P3H;
  float q1 = bf2f(pr[h * HDIM + d]);
  float q2 = bf2f(pr[h * HDIM + d + 64]);
  float k1 = bf2f(pr[HID + h * HDIM + d]);
  float k2 = bf2f(pr[HID + h * HDIM + d + 64]);
  float p = (float)pos_ids[prow];
  float invf = exp2f(-(float)d * 0.2076205059304601f);
  float ang = p * invf;
  float sn, cs;
  sincosf(ang, &sn, &cs);
  size_t base = ((size_t)(b * NHEAD + h) * SEQ + s) * HDIM + d;
  q[base]      = f2bf(q1 * cs - q2 * sn);
  q[base + 64] = f2bf(q2 * cs + q1 * sn);
  k[base]      = f2bf(k1 * cs - k2 * sn);
  k[base + 64] = f2bf(k2 * cs + k1 * sn);
}

// ---------------- V transpose: proj v-part -> vt [B,NH,HD,S] (bf16) ----------------
__global__ void k_vtrans(const u16* __restrict__ proj, u16* __restrict__ vt) {
  int wid = (blockIdx.x * 256 + threadIdx.x) >> 6;
  int lane = threadIdx.x & 63;
  int half = wid & 1;
  int s8 = (wid >> 1) & 255;
  int h = (wid >> 9) & 31;
  int b = wid >> 14;
  int d = half * 64 + lane;
  int s0 = s8 * 8;
  u16x8 v;
#pragma unroll
  for (int r = 0; r < 8; r++)
    v[r] = proj[(size_t)(b * SEQ + s0 + r) * P3H + 2 * HID + h * HDIM + d];
  *reinterpret_cast<u16x8*>(&vt[((size_t)(b * NHEAD + h) * HDIM + d) * SEQ + s0]) = v;
}

// ---------------- Flash attention (causal), swapped-QK^T, shared K/V frags ----------------
// block = (b, h, 128 q-rows); 4 waves x 32 rows (2 groups of 16). KV tiles of 64,
// double-buffered, counted vmcnt. K/V fragments read ONCE and used by both q-groups.
// Softmax in raw-score domain; SC2 folded into exp2 args via fma.
__device__ __forceinline__ void stage_kv(const u16* __restrict__ kp, const u16* __restrict__ vp,
                                         u16* ksl, u16* vsl, int kv0, int t) {
#pragma unroll
  for (int c = 0; c < 4; c++) {           // K tile 64x128
    int row = c * 16 + (t >> 4);
    int cb = (t & 15) ^ (row & 7);
    gload_lds16(kp + (size_t)(kv0 + row) * HDIM + cb * 8, ksl + (size_t)(c * 256 + t) * 8);
  }
#pragma unroll
  for (int c = 0; c < 4; c++) {           // Vt tile 128x64
    int row = c * 32 + (t >> 3);
    int cb = (t & 7) ^ (row & 7);
    gload_lds16(vp + (size_t)row * SEQ + kv0 + cb * 8, vsl + (size_t)(c * 256 + t) * 8);
  }
}

__global__ void __launch_bounds__(256, 2) k_attn(const u16* __restrict__ q,
                                                 const u16* __restrict__ k,
                                                 const u16* __restrict__ vt,
                                                 float* __restrict__ out) {
  __shared__ u16 Ks[2][64 * 128];   // 32 KB
  __shared__ u16 Vs[2][128 * 64];   // 32 KB
  __shared__ u16 Ps[4][2][16 * 64]; // 16 KB (per-wave, per-group P tile)
  const int t = threadIdx.x;
  const int w = t >> 6, lane = t & 63;
  const int li = lane & 15, lg = lane >> 4;
  const int qb = gridDim.x - 1 - blockIdx.x;   // heavy diagonal blocks first
  const int h = blockIdx.y, b = blockIdx.z;
  const int q0 = qb * 128;
  const int qw = q0 + w * 32;
  const size_t bh = (size_t)(b * NHEAD + h);
  const u16* qp = q + bh * SEQ * HDIM;
  const u16* kp = k + bh * SEQ * HDIM;
  const u16* vp = vt + bh * HDIM * SEQ;

  // Q fragments (B-operand for swapped QK^T): lane li = q-row
  s16x8 bq[2][4];
#pragma unroll
  for (int g = 0; g < 2; g++)
#pragma unroll
    for (int kk = 0; kk < 4; kk++)
      bq[g][kk] = *reinterpret_cast<const s16x8*>(
          &qp[(size_t)(qw + g * 16 + li) * HDIM + kk * 32 + lg * 8]);

  fx4 Oacc[2][8];
#pragma unroll
  for (int g = 0; g < 2; g++)
#pragma unroll
    for (int nd = 0; nd < 8; nd++) Oacc[g][nd] = fx4{0.f, 0.f, 0.f, 0.f};
  float mrun[2] = {-1e30f, -1e30f}, lrun[2] = {0.f, 0.f};

  const float SC2 = 0.12752551286084110f;       // (1/sqrt(128)) * log2(e)
  const float THR = 8.0f / SC2;                 // defer-max threshold, raw domain
  const int nt = 2 * (qb + 1);
  const int psw = (li & 7) << 4;                // P swizzle byte mask

  stage_kv(kp, vp, Ks[0], Vs[0], 0, t);

  for (int tk = 0; tk < nt; tk++) {
    const int cur = tk & 1;
    if (tk + 1 < nt) {
      stage_kv(kp, vp, Ks[cur ^ 1], Vs[cur ^ 1], (tk + 1) * 64, t);
      asm volatile("s_waitcnt vmcnt(8)" ::: "memory");   // drain tile tk only
    } else {
      asm volatile("s_waitcnt vmcnt(0)" ::: "memory");
    }
    __builtin_amdgcn_s_barrier();

    const u16* Kc = Ks[cur];
    const u16* Vc = Vs[cur];
    const int kv0 = tk * 64;
    const bool diag = (tk >= 2 * qb);

    // ---- S^T = K Q^T for BOTH q-groups, K-frags read once
    fx4 sc[2][4];
#pragma unroll
    for (int g = 0; g < 2; g++)
#pragma unroll
      for (int n = 0; n < 4; n++) sc[g][n] = fx4{0.f, 0.f, 0.f, 0.f};
    __builtin_amdgcn_s_setprio(1);
#pragma unroll
    for (int n = 0; n < 4; n++) {
      int r = n * 16 + li;
#pragma unroll
      for (int kk = 0; kk < 4; kk++) {
        s16x8 ak = *reinterpret_cast<const s16x8*>(
            &Kc[r * 128 + (((kk * 4 + lg) ^ (r & 7)) << 3)]);
        sc[0][n] = mfma16(ak, bq[0][kk], sc[0][n]);
        sc[1][n] = mfma16(ak, bq[1][kk], sc[1][n]);
      }
    }
    __builtin_amdgcn_s_setprio(0);

    // ---- causal mask (raw domain; diag = last two tiles of this q-block)
    if (diag) {
#pragma unroll
      for (int g = 0; g < 2; g++) {
        const int qg = qw + g * 16 + li;
#pragma unroll
        for (int n = 0; n < 4; n++)
#pragma unroll
          for (int j = 0; j < 4; j++) {
            int kvg = kv0 + n * 16 + lg * 4 + j;
            if (kvg > qg) sc[g][n][j] = -1e30f;
          }
      }
    }

    // ---- per-group softmax (raw-domain max; SC2 folded into exp2 via fma)
    s16x8 ap[2][2];
#pragma unroll
    for (int g = 0; g < 2; g++) {
      float mn[4];
#pragma unroll
      for (int n = 0; n < 4; n++)
        mn[n] = fmaxf(fmaxf(sc[g][n][0], sc[g][n][1]), fmaxf(sc[g][n][2], sc[g][n][3]));
      float vmax = fmaxf(fmaxf(mn[0], mn[1]), fmaxf(mn[2], mn[3]));
      vmax = fmaxf(vmax, __shfl_xor(vmax, 16));
      vmax = fmaxf(vmax, __shfl_xor(vmax, 32));
      if (__any(vmax > mrun[g] + THR)) {
        float mnew = fmaxf(mrun[g], vmax);
        float al = exp2f((mrun[g] - mnew) * SC2);
        mrun[g] = mnew;
        lrun[g] *= al;
        float alj[4];
#pragma unroll
        for (int j = 0; j < 4; j++) alj[j] = __shfl(al, lg * 4 + j);
#pragma unroll
        for (int nd = 0; nd < 8; nd++)
#pragma unroll
          for (int j = 0; j < 4; j++) Oacc[g][nd][j] *= alj[j];
      }
      const float mS = mrun[g] * SC2;
      float ps[4];
#pragma unroll
      for (int n = 0; n < 4; n++) {
        u16x4 pk;
        float pv0 = exp2f(__builtin_fmaf(sc[g][n][0], SC2, -mS));
        float pv1 = exp2f(__builtin_fmaf(sc[g][n][1], SC2, -mS));
        float pv2 = exp2f(__builtin_fmaf(sc[g][n][2], SC2, -mS));
        float pv3 = exp2f(__builtin_fmaf(sc[g][n][3], SC2, -mS));
        pk[0] = __builtin_bit_cast(u16, __float2bfloat16(pv0));
        pk[1] = __builtin_bit_cast(u16, __float2bfloat16(pv1));
        pk[2] = __builtin_bit_cast(u16, __float2bfloat16(pv2));
        pk[3] = __builtin_bit_cast(u16, __float2bfloat16(pv3));
        ps[n] = (pv0 + pv1) + (pv2 + pv3);
        *reinterpret_cast<u16x4*>(
            &Ps[w][g][li * 64 + (((n * 32 + lg * 8) ^ psw) >> 1)]) = pk;
      }
      float psum = (ps[0] + ps[1]) + (ps[2] + ps[3]);
      psum += __shfl_xor(psum, 16);
      psum += __shfl_xor(psum, 32);
      lrun[g] += psum;
#pragma unroll
      for (int kvc = 0; kvc < 2; kvc++)
        ap[g][kvc] = *reinterpret_cast<const s16x8*>(
            &Ps[w][g][li * 64 + (((kvc * 64 + lg * 16) ^ psw) >> 1)]);
    }

    // ---- O += P V for BOTH q-groups, V-frags read once
    __builtin_amdgcn_s_setprio(1);
#pragma unroll
    for (int nd = 0; nd < 8; nd++) {
      int dr = nd * 16 + li;
#pragma unroll
      for (int kvc = 0; kvc < 2; kvc++) {
        s16x8 bv = *reinterpret_cast<const s16x8*>(
            &Vc[dr * 64 + (((kvc * 4 + lg) ^ (dr & 7)) << 3)]);
        Oacc[0][nd] = mfma16(ap[0][kvc], bv, Oacc[0][nd]);
        Oacc[1][nd] = mfma16(ap[1][kvc], bv, Oacc[1][nd]);
      }
    }
    __builtin_amdgcn_s_setprio(0);

    __builtin_amdgcn_s_barrier();
    __builtin_amdgcn_sched_barrier(0);   // keep next iter's STAGE below this barrier
  }

  // ---- epilogue: fetch lrun for output rows (lg,j) via shfl, normalize, store
#pragma unroll
  for (int g = 0; g < 2; g++)
#pragma unroll
    for (int j = 0; j < 4; j++) {
      float rl = 1.0f / __shfl(lrun[g], lg * 4 + j);
      int s = qw + g * 16 + lg * 4 + j;
      float* op = out + ((size_t)(b * SEQ) + s) * HID + h * HDIM;
#pragma unroll
      for (int nd = 0; nd < 8; nd++) op[nd * 16 + li] = Oacc[g][nd][j] * rl;
    }
}

extern "C" void kernel_launch(void* const* d_in, const int* in_sizes, int n_in,
                              void* d_out, int out_size, void* d_ws, size_t ws_size,
                              hipStream_t stream) {
  const float* hidden = (const float*)d_in[0];
  const float* wpack = (const float*)d_in[1];
  const int* pos = (const int*)d_in[3];
  float* out = (float*)d_out;

  char* ws = (char*)d_ws;
  u16* hid_bf = (u16*)ws;
  u16* wp_bf = (u16*)(ws + ((size_t)32 << 20));
  u16* qb = (u16*)ws;
  u16* kb = (u16*)(ws + ((size_t)32 << 20));
  u16* vtb = (u16*)(ws + ((size_t)64 << 20));
  u16* proj = (u16*)(ws + ((size_t)128 << 20));

  k_cvt<<<(HID * HID / 4 + 255) / 256, 256, 0, stream>>>(hidden, hid_bf, HID * HID / 4);
  k_cvt<<<(P3H * HID / 4 + 255) / 256, 256, 0, stream>>>(wpack, wp_bf, P3H * HID / 4);

  k_gemm_qkv<<<768, 512, 0, stream>>>(hid_bf, wp_bf, proj);

  k_rope<<<(2 * SEQ * NHEAD * 64) / 256, 256, 0, stream>>>(proj, qb, kb, pos);
  k_vtrans<<<(2 * NHEAD * (SEQ / 8) * 2) / 4, 256, 0, stream>>>(proj, vtb);

  dim3 ga(SEQ / 128, NHEAD, 2);
  k_attn<<<ga, 256, 0, stream>>>(qb, kb, vtb, out);
}